// Round 2
// baseline (4090.792 us; speedup 1.0000x reference)
//
#include <hip/hip_runtime.h>
#include <hip/hip_bf16.h>

#define N_NODES 100000
#define N_EDGES 1600000
#define KITER   10
#define ALPHA   0.1f
#define MX      256   // input feature dim
#define MH      64    // hidden dim
#define MY      64    // output feature dim

static __device__ __forceinline__ float us2f(unsigned short u) {
    union { unsigned int i; float f; } v; v.i = ((unsigned int)u) << 16; return v.f;
}
static __device__ __forceinline__ unsigned short f2us(float f) {
    union { float f; unsigned int i; } v; v.f = f;
    unsigned int x = v.i;
    unsigned int r = (x + 0x7fffu + ((x >> 16) & 1u)) >> 16;  // RNE
    return (unsigned short)r;
}
static __device__ __forceinline__ float loadf(const void* p, size_t i, int f32) {
    return f32 ? ((const float*)p)[i] : us2f(((const unsigned short*)p)[i]);
}

// ---------------------------------------------------------------------------
// Runtime dtype detection.
// flags[0] = 1 if float inputs are fp32 (else packed bf16)
// flags[1] = 1 if edge_index is int64 (else int32)
// ---------------------------------------------------------------------------
__global__ __launch_bounds__(256) void detect_kernel(
    const void* __restrict__ x, const int* __restrict__ ei, int* __restrict__ flags)
{
    __shared__ int cnt_weird, cnt_nz_odd;
    const int tid = threadIdx.x;
    if (tid == 0) { cnt_weird = 0; cnt_nz_odd = 0; }
    __syncthreads();
    const unsigned short* xu = (const unsigned short*)x;
    int w = 0, nz = 0;
    for (int i = tid; i < 512; i += 256) {
        unsigned e = (xu[2 * i] >> 7) & 0xFFu;     // exponent field if bf16
        if (e != 0u && (e < 105u || e > 141u)) w++;
        if (ei[2 * i + 1] != 0) nz++;              // high word if int64
    }
    atomicAdd(&cnt_weird, w);
    atomicAdd(&cnt_nz_odd, nz);
    __syncthreads();
    if (tid == 0) {
        flags[0] = (cnt_weird > 64) ? 1 : 0;
        flags[1] = (cnt_nz_odd == 0) ? 1 : 0;
    }
}

// ---------------------------------------------------------------------------
// MLP: h0 = relu(x@W1^T + b1)@W2^T + b2. Block = 4 waves; wave = one node,
// lane = output feature. Weights staged transposed (bf16) in LDS.
// ---------------------------------------------------------------------------
__global__ __launch_bounds__(256) void mlp_kernel(
    const void* __restrict__ x,
    const void* __restrict__ W1,
    const void* __restrict__ b1,
    const void* __restrict__ W2,
    const void* __restrict__ b2,
    const int* __restrict__ flags,
    float* __restrict__ h0)
{
    __shared__ unsigned short W1t[MX][MH];   // 32 KB, [k][j]
    __shared__ unsigned short W2t[MH][MY];   // 8 KB,  [k][j]
    __shared__ float xs[4][MX];              // 4 KB
    __shared__ float h1s[4][MH];             // 1 KB

    const int f32 = flags[0];
    const int tid = threadIdx.x;
    for (int idx = tid; idx < MH * MX; idx += 256) {
        int j = idx / MX, k = idx % MX;      // W1[j][k]
        float v = loadf(W1, idx, f32);
        W1t[k][j] = f2us(v);
    }
    for (int idx = tid; idx < MY * MH; idx += 256) {
        int j = idx / MH, k = idx % MH;      // W2[j][k]
        float v = loadf(W2, idx, f32);
        W2t[k][j] = f2us(v);
    }
    const int j    = tid & 63;
    const int slot = tid >> 6;
    const float b1j = loadf(b1, j, f32);
    const float b2j = loadf(b2, j, f32);
    __syncthreads();

    for (int base = blockIdx.x * 4; base < N_NODES; base += gridDim.x * 4) {
        const int n = base + slot;
        if (n < N_NODES) {
            float4 xv;
            if (f32) {
                xv = ((const float4*)((const float*)x + (size_t)n * MX))[j];
            } else {
                const ushort4 v = ((const ushort4*)((const unsigned short*)x + (size_t)n * MX))[j];
                xv.x = us2f(v.x); xv.y = us2f(v.y); xv.z = us2f(v.z); xv.w = us2f(v.w);
            }
            ((float4*)&xs[slot][0])[j] = xv;
        }
        __syncthreads();
        if (n < N_NODES) {
            float acc = b1j;
            #pragma unroll 8
            for (int k = 0; k < MX; ++k)
                acc += xs[slot][k] * us2f(W1t[k][j]);
            h1s[slot][j] = fmaxf(acc, 0.0f);
        }
        __syncthreads();
        if (n < N_NODES) {
            float acc = b2j;
            #pragma unroll 8
            for (int k = 0; k < MH; ++k)
                acc += h1s[slot][k] * us2f(W2t[k][j]);
            h0[(size_t)n * MY + j] = acc;
        }
        __syncthreads();
    }
}

// ---------------------------------------------------------------------------
__global__ __launch_bounds__(256) void zero_deg_kernel(int* __restrict__ deg) {
    int i = blockIdx.x * 256 + threadIdx.x;
    if (i < N_NODES) deg[i] = 0;
}

__global__ __launch_bounds__(256) void deg_kernel(
    const int* __restrict__ ei, const int* __restrict__ flags, int* __restrict__ deg)
{
    int e = blockIdx.x * 256 + threadIdx.x;
    if (e < N_EDGES) {
        int i64 = flags[1];
        int d = i64 ? ei[2 * (N_EDGES + e)] : ei[N_EDGES + e];
        atomicAdd(&deg[d], 1);
    }
}

__global__ __launch_bounds__(256) void dinv_kernel(
    const int* __restrict__ deg, float* __restrict__ dinv)
{
    int i = blockIdx.x * 256 + threadIdx.x;
    if (i < N_NODES) dinv[i] = rsqrtf((float)(deg[i] + 1)); // +1 self loop
}

// h_out = ALPHA*h0 + (1-ALPHA)*dinv[i]^2 * h_in   (self-loop + teleport)
__global__ __launch_bounds__(256) void self_kernel(
    const float4* __restrict__ h0, const float4* __restrict__ hin,
    const float* __restrict__ dinv, float4* __restrict__ hout)
{
    int idx = blockIdx.x * 256 + threadIdx.x;      // one float4 (4 feats)
    if (idx >= N_NODES * (MY / 4)) return;
    int node = idx / (MY / 4);
    float d = dinv[node];
    float w = (1.0f - ALPHA) * d * d;
    float4 a = h0[idx], b = hin[idx];
    float4 o;
    o.x = ALPHA * a.x + w * b.x;
    o.y = ALPHA * a.y + w * b.y;
    o.z = ALPHA * a.z + w * b.z;
    o.w = ALPHA * a.w + w * b.w;
    hout[idx] = o;
}

// one wave per edge, lane = feature
__global__ __launch_bounds__(256) void edge_kernel(
    const int* __restrict__ ei, const int* __restrict__ flags,
    const float* __restrict__ dinv,
    const float* __restrict__ hin, float* __restrict__ hout)
{
    int lane = threadIdx.x & 63;
    int e = blockIdx.x * 4 + (threadIdx.x >> 6);
    if (e >= N_EDGES) return;
    int i64 = flags[1];
    int s, d;
    if (i64) { s = ei[2 * e]; d = ei[2 * (N_EDGES + e)]; }
    else     { s = ei[e];     d = ei[N_EDGES + e]; }
    float w = (1.0f - ALPHA) * dinv[s] * dinv[d];
    float v = w * hin[(size_t)s * MY + lane];
    atomicAdd(&hout[(size_t)d * MY + lane], v);
}

__global__ __launch_bounds__(256) void out_kernel(
    const float* __restrict__ h, void* __restrict__ out, const int* __restrict__ flags)
{
    int idx = blockIdx.x * 256 + threadIdx.x;
    if (idx < N_NODES * MY) {
        float v = h[idx];
        if (flags[0]) ((float*)out)[idx] = v;
        else          ((unsigned short*)out)[idx] = f2us(v);
    }
}

// ---------------------------------------------------------------------------
extern "C" void kernel_launch(void* const* d_in, const int* in_sizes, int n_in,
                              void* d_out, int out_size, void* d_ws, size_t ws_size,
                              hipStream_t stream)
{
    const void* x  = d_in[0];
    const void* W1 = d_in[1];
    const void* b1 = d_in[2];
    const void* W2 = d_in[3];
    const void* b2 = d_in[4];
    const int*  ei = (const int*)d_in[5];

    // workspace layout: flags(256B) | h0 | hA | hB | dinv | deg  (~77.6 MB fp32)
    int*   flags = (int*)d_ws;
    float* h0    = (float*)((char*)d_ws + 256);
    float* hA    = h0 + (size_t)N_NODES * MY;
    float* hB    = hA + (size_t)N_NODES * MY;
    float* dinv  = hB + (size_t)N_NODES * MY;
    int*   deg   = (int*)(dinv + N_NODES);

    detect_kernel<<<1, 256, 0, stream>>>(x, ei, flags);
    zero_deg_kernel<<<(N_NODES + 255) / 256, 256, 0, stream>>>(deg);
    mlp_kernel<<<2048, 256, 0, stream>>>(x, W1, b1, W2, b2, flags, h0);
    deg_kernel<<<(N_EDGES + 255) / 256, 256, 0, stream>>>(ei, flags, deg);
    dinv_kernel<<<(N_NODES + 255) / 256, 256, 0, stream>>>(deg, dinv);

    const float* hin = h0;
    float* hout = hA;
    const int n_f4 = N_NODES * (MY / 4);
    for (int k = 0; k < KITER; ++k) {
        self_kernel<<<(n_f4 + 255) / 256, 256, 0, stream>>>(
            (const float4*)h0, (const float4*)hin, dinv, (float4*)hout);
        edge_kernel<<<(N_EDGES + 3) / 4, 256, 0, stream>>>(ei, flags, dinv, hin, hout);
        hin = hout;
        hout = (hout == hA) ? hB : hA;
    }
    out_kernel<<<(N_NODES * MY + 255) / 256, 256, 0, stream>>>(hin, d_out, flags);
}

// Round 3
// 1817.398 us; speedup vs baseline: 2.2509x; 2.2509x over previous
//
#include <hip/hip_runtime.h>
#include <hip/hip_bf16.h>

#define N_NODES 100000
#define N_EDGES 1600000
#define KITER   10
#define ALPHA   0.1f
#define MX      256   // input feature dim
#define MH      64    // hidden dim
#define MY      64    // output feature dim

static __device__ __forceinline__ float us2f(unsigned short u) {
    union { unsigned int i; float f; } v; v.i = ((unsigned int)u) << 16; return v.f;
}
static __device__ __forceinline__ unsigned short f2us(float f) {
    union { float f; unsigned int i; } v; v.f = f;
    unsigned int x = v.i;
    unsigned int r = (x + 0x7fffu + ((x >> 16) & 1u)) >> 16;  // RNE
    return (unsigned short)r;
}
static __device__ __forceinline__ float loadf(const void* p, size_t i, int f32) {
    return f32 ? ((const float*)p)[i] : us2f(((const unsigned short*)p)[i]);
}

// ---------------------------------------------------------------------------
// Runtime dtype detection.
// flags[0] = 1 if float inputs are fp32 (else packed bf16)
// flags[1] = 1 if edge_index is int64 (else int32)
// ---------------------------------------------------------------------------
__global__ __launch_bounds__(256) void detect_kernel(
    const void* __restrict__ x, const int* __restrict__ ei, int* __restrict__ flags)
{
    __shared__ int cnt_weird, cnt_nz_odd;
    const int tid = threadIdx.x;
    if (tid == 0) { cnt_weird = 0; cnt_nz_odd = 0; }
    __syncthreads();
    const unsigned short* xu = (const unsigned short*)x;
    int w = 0, nz = 0;
    for (int i = tid; i < 512; i += 256) {
        unsigned e = (xu[2 * i] >> 7) & 0xFFu;     // exponent field if bf16
        if (e != 0u && (e < 105u || e > 141u)) w++;
        if (ei[2 * i + 1] != 0) nz++;              // high word if int64
    }
    atomicAdd(&cnt_weird, w);
    atomicAdd(&cnt_nz_odd, nz);
    __syncthreads();
    if (tid == 0) {
        flags[0] = (cnt_weird > 64) ? 1 : 0;
        flags[1] = (cnt_nz_odd == 0) ? 1 : 0;
    }
}

// ---------------------------------------------------------------------------
// MLP: h0 = relu(x@W1^T + b1)@W2^T + b2. Block = 4 waves; wave = one node,
// lane = output feature. Weights staged transposed (bf16) in LDS.
// ---------------------------------------------------------------------------
__global__ __launch_bounds__(256) void mlp_kernel(
    const void* __restrict__ x,
    const void* __restrict__ W1,
    const void* __restrict__ b1,
    const void* __restrict__ W2,
    const void* __restrict__ b2,
    const int* __restrict__ flags,
    float* __restrict__ h0)
{
    __shared__ unsigned short W1t[MX][MH];   // 32 KB, [k][j]
    __shared__ unsigned short W2t[MH][MY];   // 8 KB,  [k][j]
    __shared__ float xs[4][MX];              // 4 KB
    __shared__ float h1s[4][MH];             // 1 KB

    const int f32 = flags[0];
    const int tid = threadIdx.x;
    for (int idx = tid; idx < MH * MX; idx += 256) {
        int j = idx / MX, k = idx % MX;      // W1[j][k]
        W1t[k][j] = f2us(loadf(W1, idx, f32));
    }
    for (int idx = tid; idx < MY * MH; idx += 256) {
        int j = idx / MH, k = idx % MH;      // W2[j][k]
        W2t[k][j] = f2us(loadf(W2, idx, f32));
    }
    const int j    = tid & 63;
    const int slot = tid >> 6;
    const float b1j = loadf(b1, j, f32);
    const float b2j = loadf(b2, j, f32);
    __syncthreads();

    for (int base = blockIdx.x * 4; base < N_NODES; base += gridDim.x * 4) {
        const int n = base + slot;
        if (n < N_NODES) {
            float4 xv;
            if (f32) {
                xv = ((const float4*)((const float*)x + (size_t)n * MX))[j];
            } else {
                const ushort4 v = ((const ushort4*)((const unsigned short*)x + (size_t)n * MX))[j];
                xv.x = us2f(v.x); xv.y = us2f(v.y); xv.z = us2f(v.z); xv.w = us2f(v.w);
            }
            ((float4*)&xs[slot][0])[j] = xv;
        }
        __syncthreads();
        if (n < N_NODES) {
            float acc = b1j;
            #pragma unroll 8
            for (int k = 0; k < MX; ++k)
                acc += xs[slot][k] * us2f(W1t[k][j]);
            h1s[slot][j] = fmaxf(acc, 0.0f);
        }
        __syncthreads();
        if (n < N_NODES) {
            float acc = b2j;
            #pragma unroll 8
            for (int k = 0; k < MH; ++k)
                acc += h1s[slot][k] * us2f(W2t[k][j]);
            h0[(size_t)n * MY + j] = acc;
        }
        __syncthreads();
    }
}

// ---------------------------------------------------------------------------
__global__ __launch_bounds__(256) void zero_deg_kernel(int* __restrict__ deg) {
    int i = blockIdx.x * 256 + threadIdx.x;
    if (i < N_NODES) deg[i] = 0;
}

__global__ __launch_bounds__(256) void deg_kernel(
    const int* __restrict__ ei, const int* __restrict__ flags, int* __restrict__ deg)
{
    int e = blockIdx.x * 256 + threadIdx.x;
    if (e < N_EDGES) {
        int d = flags[1] ? ei[2 * (N_EDGES + e)] : ei[N_EDGES + e];
        atomicAdd(&deg[d], 1);
    }
}

__global__ __launch_bounds__(256) void dinv_kernel(
    const int* __restrict__ deg, float* __restrict__ dinv)
{
    int i = blockIdx.x * 256 + threadIdx.x;
    if (i < N_NODES) dinv[i] = rsqrtf((float)(deg[i] + 1)); // +1 self loop
}

// Single-block exclusive scan of deg -> rowptr; zeroes fill counters.
__global__ __launch_bounds__(256) void scan_kernel(
    const int* __restrict__ deg, int* __restrict__ rowptr, int* __restrict__ fill)
{
    __shared__ int partial[256];
    const int tid = threadIdx.x;
    const int CHUNK = (N_NODES + 255) / 256;
    const int beg = tid * CHUNK;
    const int end = min(beg + CHUNK, N_NODES);
    int s = 0;
    for (int i = beg; i < end; ++i) s += deg[i];
    partial[tid] = s;
    __syncthreads();
    if (tid == 0) {
        int run = 0;
        for (int t = 0; t < 256; ++t) { int v = partial[t]; partial[t] = run; run += v; }
    }
    __syncthreads();
    int run = partial[tid];
    for (int i = beg; i < end; ++i) { rowptr[i] = run; run += deg[i]; fill[i] = 0; }
    if (tid == 255) rowptr[N_NODES] = run;
}

// Scatter edges into dst-sorted CSR: csr[pos] = {src, (1-a)*dinv[s]*dinv[d]}
__global__ __launch_bounds__(256) void fill_kernel(
    const int* __restrict__ ei, const int* __restrict__ flags,
    const float* __restrict__ dinv, const int* __restrict__ rowptr,
    int* __restrict__ fill, int2* __restrict__ csr)
{
    int e = blockIdx.x * 256 + threadIdx.x;
    if (e >= N_EDGES) return;
    int s, d;
    if (flags[1]) { s = ei[2 * e]; d = ei[2 * (N_EDGES + e)]; }
    else          { s = ei[e];     d = ei[N_EDGES + e]; }
    float w = (1.0f - ALPHA) * dinv[s] * dinv[d];
    int pos = rowptr[d] + atomicAdd(&fill[d], 1);
    csr[pos] = make_int2(s, __float_as_int(w));
}

// hout[i] = sum_e w_e*hin[src_e] + (1-a)*dinv[i]^2*hin[i] + a*h0[i]
// One wave per node, lane = feature.
__global__ __launch_bounds__(256) void pull_kernel(
    const int* __restrict__ rowptr, const int2* __restrict__ csr,
    const float* __restrict__ dinv,
    const float* __restrict__ h0, const float* __restrict__ hin,
    float* __restrict__ hout)
{
    const int lane = threadIdx.x & 63;
    const int node = blockIdx.x * 4 + (threadIdx.x >> 6);
    if (node >= N_NODES) return;
    int p   = rowptr[node];
    int end = rowptr[node + 1];
    float acc = 0.0f;
    for (; p + 1 < end; p += 2) {
        int2 e0 = csr[p], e1 = csr[p + 1];
        float v0 = hin[(size_t)e0.x * MY + lane];
        float v1 = hin[(size_t)e1.x * MY + lane];
        acc += __int_as_float(e0.y) * v0;
        acc += __int_as_float(e1.y) * v1;
    }
    if (p < end) {
        int2 e = csr[p];
        acc += __int_as_float(e.y) * hin[(size_t)e.x * MY + lane];
    }
    const size_t o = (size_t)node * MY + lane;
    float dv = dinv[node];
    hout[o] = acc + (1.0f - ALPHA) * dv * dv * hin[o] + ALPHA * h0[o];
}

// ---- fallback (atomic push) kernels, used only if ws too small ------------
__global__ __launch_bounds__(256) void self_kernel(
    const float4* __restrict__ h0, const float4* __restrict__ hin,
    const float* __restrict__ dinv, float4* __restrict__ hout)
{
    int idx = blockIdx.x * 256 + threadIdx.x;
    if (idx >= N_NODES * (MY / 4)) return;
    int node = idx / (MY / 4);
    float d = dinv[node];
    float w = (1.0f - ALPHA) * d * d;
    float4 a = h0[idx], b = hin[idx];
    float4 o;
    o.x = ALPHA * a.x + w * b.x;
    o.y = ALPHA * a.y + w * b.y;
    o.z = ALPHA * a.z + w * b.z;
    o.w = ALPHA * a.w + w * b.w;
    hout[idx] = o;
}

__global__ __launch_bounds__(256) void edge_kernel(
    const int* __restrict__ ei, const int* __restrict__ flags,
    const float* __restrict__ dinv,
    const float* __restrict__ hin, float* __restrict__ hout)
{
    int lane = threadIdx.x & 63;
    int e = blockIdx.x * 4 + (threadIdx.x >> 6);
    if (e >= N_EDGES) return;
    int s, d;
    if (flags[1]) { s = ei[2 * e]; d = ei[2 * (N_EDGES + e)]; }
    else          { s = ei[e];     d = ei[N_EDGES + e]; }
    float w = (1.0f - ALPHA) * dinv[s] * dinv[d];
    atomicAdd(&hout[(size_t)d * MY + lane], w * hin[(size_t)s * MY + lane]);
}

__global__ __launch_bounds__(256) void out_kernel(
    const float* __restrict__ h, void* __restrict__ out, const int* __restrict__ flags)
{
    int idx = blockIdx.x * 256 + threadIdx.x;
    if (idx < N_NODES * MY) {
        float v = h[idx];
        if (flags[0]) ((float*)out)[idx] = v;
        else          ((unsigned short*)out)[idx] = f2us(v);
    }
}

// ---------------------------------------------------------------------------
extern "C" void kernel_launch(void* const* d_in, const int* in_sizes, int n_in,
                              void* d_out, int out_size, void* d_ws, size_t ws_size,
                              hipStream_t stream)
{
    const void* x  = d_in[0];
    const void* W1 = d_in[1];
    const void* b1 = d_in[2];
    const void* W2 = d_in[3];
    const void* b2 = d_in[4];
    const int*  ei = (const int*)d_in[5];

    const size_t HN = (size_t)N_NODES * MY;    // 6.4M floats
    // layout: flags(256B) | h0 | hA | hB | dinv | deg | rowptr | fill | csr
    char* base = (char*)d_ws;
    int*   flags  = (int*)base;                     base += 256;
    float* h0     = (float*)base;                   base += HN * 4;
    float* hA     = (float*)base;                   base += HN * 4;
    float* hB     = (float*)base;                   base += HN * 4;
    float* dinv   = (float*)base;                   base += (size_t)N_NODES * 4;
    int*   deg    = (int*)base;                     base += (size_t)N_NODES * 4;
    int*   rowptr = (int*)base;                     base += ((size_t)N_NODES + 4) * 4;
    int*   fill   = (int*)base;                     base += (size_t)N_NODES * 4;
    int2*  csr    = (int2*)base;                    base += (size_t)N_EDGES * 8;
    const size_t need_csr = (size_t)(base - (char*)d_ws);
    const bool use_csr = ws_size >= need_csr;

    detect_kernel<<<1, 256, 0, stream>>>(x, ei, flags);
    zero_deg_kernel<<<(N_NODES + 255) / 256, 256, 0, stream>>>(deg);
    mlp_kernel<<<2048, 256, 0, stream>>>(x, W1, b1, W2, b2, flags, h0);
    deg_kernel<<<(N_EDGES + 255) / 256, 256, 0, stream>>>(ei, flags, deg);
    dinv_kernel<<<(N_NODES + 255) / 256, 256, 0, stream>>>(deg, dinv);

    const float* hin = h0;
    float* hout = hA;
    if (use_csr) {
        scan_kernel<<<1, 256, 0, stream>>>(deg, rowptr, fill);
        fill_kernel<<<(N_EDGES + 255) / 256, 256, 0, stream>>>(
            ei, flags, dinv, rowptr, fill, csr);
        for (int k = 0; k < KITER; ++k) {
            pull_kernel<<<(N_NODES + 3) / 4, 256, 0, stream>>>(
                rowptr, csr, dinv, h0, hin, hout);
            hin = hout;
            hout = (hout == hA) ? hB : hA;
        }
    } else {
        const int n_f4 = N_NODES * (MY / 4);
        for (int k = 0; k < KITER; ++k) {
            self_kernel<<<(n_f4 + 255) / 256, 256, 0, stream>>>(
                (const float4*)h0, (const float4*)hin, dinv, (float4*)hout);
            edge_kernel<<<(N_EDGES + 3) / 4, 256, 0, stream>>>(ei, flags, dinv, hin, hout);
            hin = hout;
            hout = (hout == hA) ? hB : hA;
        }
    }
    out_kernel<<<(N_NODES * MY + 255) / 256, 256, 0, stream>>>(hin, d_out, flags);
}

// Round 4
// 1401.153 us; speedup vs baseline: 2.9196x; 1.2971x over previous
//
#include <hip/hip_runtime.h>
#include <hip/hip_bf16.h>

#define N_NODES 100000
#define N_EDGES 1600000
#define KITER   10
#define ALPHA   0.1f
#define MX      256   // input feature dim
#define MH      64    // hidden dim
#define MY      64    // output feature dim

typedef __attribute__((ext_vector_type(8))) short bf16x8;   // 8 bf16 = 4 VGPRs
typedef __attribute__((ext_vector_type(4))) float f32x4;

static __device__ __forceinline__ float us2f(unsigned short u) {
    union { unsigned int i; float f; } v; v.i = ((unsigned int)u) << 16; return v.f;
}
static __device__ __forceinline__ unsigned short f2us(float f) {
    union { float f; unsigned int i; } v; v.f = f;
    unsigned int x = v.i;
    unsigned int r = (x + 0x7fffu + ((x >> 16) & 1u)) >> 16;  // RNE
    return (unsigned short)r;
}
static __device__ __forceinline__ float loadf(const void* p, size_t i, int f32) {
    return f32 ? ((const float*)p)[i] : us2f(((const unsigned short*)p)[i]);
}

// ---------------------------------------------------------------------------
// Runtime dtype detection.
// flags[0] = 1 if float inputs are fp32 (else packed bf16)
// flags[1] = 1 if edge_index is int64 (else int32)
// ---------------------------------------------------------------------------
__global__ __launch_bounds__(256) void detect_kernel(
    const void* __restrict__ x, const int* __restrict__ ei, int* __restrict__ flags)
{
    __shared__ int cnt_weird, cnt_nz_odd;
    const int tid = threadIdx.x;
    if (tid == 0) { cnt_weird = 0; cnt_nz_odd = 0; }
    __syncthreads();
    const unsigned short* xu = (const unsigned short*)x;
    int w = 0, nz = 0;
    for (int i = tid; i < 512; i += 256) {
        unsigned e = (xu[2 * i] >> 7) & 0xFFu;     // exponent field if bf16
        if (e != 0u && (e < 105u || e > 141u)) w++;
        if (ei[2 * i + 1] != 0) nz++;              // high word if int64
    }
    atomicAdd(&cnt_weird, w);
    atomicAdd(&cnt_nz_odd, nz);
    __syncthreads();
    if (tid == 0) {
        flags[0] = (cnt_weird > 64) ? 1 : 0;
        flags[1] = (cnt_nz_odd == 0) ? 1 : 0;
    }
}

// ---------------------------------------------------------------------------
// MFMA MLP. Block = 256 threads = 4 waves, 64-node tile, grid-stride.
// Layer1: C1[64,64] = X[64,256]*W1^T  (8 k-steps of 16x16x32 bf16 mfma)
// Layer2: C2[64,64] = relu(C1)[64,64]*W2^T (2 k-steps)
// LDS rows padded +8 bf16 (16B) -> b128 frag reads, 2-way bank alias (free).
// ---------------------------------------------------------------------------
#define XS_LD  (MX + 8)   // 264
#define H1_LD  (MH + 8)   // 72
__global__ __launch_bounds__(256) void mlp2_kernel(
    const void* __restrict__ x,
    const void* __restrict__ W1,
    const void* __restrict__ b1,
    const void* __restrict__ W2,
    const void* __restrict__ b2,
    const int* __restrict__ flags,
    float* __restrict__ h0)
{
    __shared__ unsigned short Xs[64][XS_LD];     // 33 KB
    __shared__ unsigned short W1s[MH][XS_LD];    // 33 KB  W1[j][k] row-major
    __shared__ unsigned short H1s[64][H1_LD];    // 9 KB
    __shared__ unsigned short W2s[MY][H1_LD];    // 9 KB   W2[j][k] row-major
    __shared__ float b1s[MH];
    __shared__ float b2s[MY];

    const int f32  = flags[0];
    const int tid  = threadIdx.x;
    const int wave = tid >> 6;
    const int lane = tid & 63;
    const int l16  = lane & 15;
    const int quad = lane >> 4;

    // stage weights once per block
    for (int i = tid; i < MH * MX; i += 256) {
        int j = i >> 8, k = i & 255;
        W1s[j][k] = f2us(loadf(W1, i, f32));
    }
    for (int i = tid; i < MY * MH; i += 256) {
        int j = i >> 6, k = i & 63;
        W2s[j][k] = f2us(loadf(W2, i, f32));
    }
    if (tid < MH) b1s[tid] = loadf(b1, tid, f32);
    else if (tid < MH + MY) b2s[tid - MH] = loadf(b2, tid - MH, f32);
    __syncthreads();

    const int n_tiles = (N_NODES + 63) / 64;
    for (int tile = blockIdx.x; tile < n_tiles; tile += gridDim.x) {
        const int base = tile * 64;
        // ---- stage X tile (zero-pad beyond N) ----
        if (f32) {
            for (int i = tid; i < 64 * 64; i += 256) {      // float4 chunks
                int r = i >> 6, c = i & 63;
                int gr = base + r;
                float4 v = make_float4(0.f, 0.f, 0.f, 0.f);
                if (gr < N_NODES)
                    v = ((const float4*)((const float*)x + (size_t)gr * MX))[c];
                ushort4 u;
                u.x = f2us(v.x); u.y = f2us(v.y); u.z = f2us(v.z); u.w = f2us(v.w);
                *(ushort4*)&Xs[r][c * 4] = u;
            }
        } else {
            for (int i = tid; i < 64 * 32; i += 256) {      // 16B chunks
                int r = i >> 5, c = i & 31;
                int gr = base + r;
                uint4 v = make_uint4(0u, 0u, 0u, 0u);
                if (gr < N_NODES)
                    v = ((const uint4*)((const unsigned short*)x + (size_t)gr * MX))[c];
                *(uint4*)&Xs[r][c * 8] = v;
            }
        }
        __syncthreads();

        // ---- layer 1: 8 k-steps, 4 col-blocks ----
        f32x4 acc[4] = {{0,0,0,0},{0,0,0,0},{0,0,0,0},{0,0,0,0}};
        const int arow = wave * 16 + l16;
        #pragma unroll
        for (int s = 0; s < 8; ++s) {
            const int k0 = s * 32 + quad * 8;
            bf16x8 a = *(const bf16x8*)&Xs[arow][k0];
            #pragma unroll
            for (int cb = 0; cb < 4; ++cb) {
                bf16x8 b = *(const bf16x8*)&W1s[cb * 16 + l16][k0];
                acc[cb] = __builtin_amdgcn_mfma_f32_16x16x32_bf16(a, b, acc[cb], 0, 0, 0);
            }
        }
        // relu + bias -> H1s (bf16)
        #pragma unroll
        for (int cb = 0; cb < 4; ++cb) {
            #pragma unroll
            for (int reg = 0; reg < 4; ++reg) {
                int row = wave * 16 + quad * 4 + reg;
                int col = cb * 16 + l16;
                float v = fmaxf(acc[cb][reg] + b1s[col], 0.0f);
                H1s[row][col] = f2us(v);
            }
        }
        // ---- layer 2: 2 k-steps, 4 col-blocks (wave-local rows; no barrier) ----
        f32x4 acc2[4] = {{0,0,0,0},{0,0,0,0},{0,0,0,0},{0,0,0,0}};
        #pragma unroll
        for (int s = 0; s < 2; ++s) {
            const int k0 = s * 32 + quad * 8;
            bf16x8 a = *(const bf16x8*)&H1s[arow][k0];
            #pragma unroll
            for (int cb = 0; cb < 4; ++cb) {
                bf16x8 b = *(const bf16x8*)&W2s[cb * 16 + l16][k0];
                acc2[cb] = __builtin_amdgcn_mfma_f32_16x16x32_bf16(a, b, acc2[cb], 0, 0, 0);
            }
        }
        #pragma unroll
        for (int cb = 0; cb < 4; ++cb) {
            #pragma unroll
            for (int reg = 0; reg < 4; ++reg) {
                int row = wave * 16 + quad * 4 + reg;
                int col = cb * 16 + l16;
                int gr = base + row;
                if (gr < N_NODES)
                    h0[(size_t)gr * MY + col] = acc2[cb][reg] + b2s[col];
            }
        }
        __syncthreads();   // protect Xs/H1s before next tile
    }
}

// ---------------------------------------------------------------------------
__global__ __launch_bounds__(256) void zero_deg_kernel(int* __restrict__ deg) {
    int i = blockIdx.x * 256 + threadIdx.x;
    if (i < N_NODES) deg[i] = 0;
}

__global__ __launch_bounds__(256) void deg_kernel(
    const int* __restrict__ ei, const int* __restrict__ flags, int* __restrict__ deg)
{
    int e = blockIdx.x * 256 + threadIdx.x;
    if (e < N_EDGES) {
        int d = flags[1] ? ei[2 * (N_EDGES + e)] : ei[N_EDGES + e];
        atomicAdd(&deg[d], 1);
    }
}

__global__ __launch_bounds__(256) void dinv_kernel(
    const int* __restrict__ deg, float* __restrict__ dinv)
{
    int i = blockIdx.x * 256 + threadIdx.x;
    if (i < N_NODES) dinv[i] = rsqrtf((float)(deg[i] + 1)); // +1 self loop
}

// Single-block exclusive scan of deg -> rowptr; zeroes fill counters.
__global__ __launch_bounds__(256) void scan_kernel(
    const int* __restrict__ deg, int* __restrict__ rowptr, int* __restrict__ fill)
{
    __shared__ int partial[256];
    const int tid = threadIdx.x;
    const int CHUNK = (N_NODES + 255) / 256;
    const int beg = tid * CHUNK;
    const int end = min(beg + CHUNK, N_NODES);
    int s = 0;
    for (int i = beg; i < end; ++i) s += deg[i];
    partial[tid] = s;
    __syncthreads();
    if (tid == 0) {
        int run = 0;
        for (int t = 0; t < 256; ++t) { int v = partial[t]; partial[t] = run; run += v; }
    }
    __syncthreads();
    int run = partial[tid];
    for (int i = beg; i < end; ++i) { rowptr[i] = run; run += deg[i]; fill[i] = 0; }
    if (tid == 255) rowptr[N_NODES] = run;
}

// Scatter edges into dst-sorted CSR: csr[pos] = {src, (1-a)*dinv[s]*dinv[d]}
__global__ __launch_bounds__(256) void fill_kernel(
    const int* __restrict__ ei, const int* __restrict__ flags,
    const float* __restrict__ dinv, const int* __restrict__ rowptr,
    int* __restrict__ fill, int2* __restrict__ csr)
{
    int e = blockIdx.x * 256 + threadIdx.x;
    if (e >= N_EDGES) return;
    int s, d;
    if (flags[1]) { s = ei[2 * e]; d = ei[2 * (N_EDGES + e)]; }
    else          { s = ei[e];     d = ei[N_EDGES + e]; }
    float w = (1.0f - ALPHA) * dinv[s] * dinv[d];
    int pos = rowptr[d] + atomicAdd(&fill[d], 1);
    csr[pos] = make_int2(s, __float_as_int(w));
}

// hout[i] = sum_e w_e*hin[src_e] + (1-a)*dinv[i]^2*hin[i] + a*h0[i]
// One wave per node, lane = feature. 4 gathers in flight.
// If write_out: emit final dtype to outp instead of hout.
__global__ __launch_bounds__(256) void pull_kernel(
    const int* __restrict__ rowptr, const int2* __restrict__ csr,
    const float* __restrict__ dinv,
    const float* __restrict__ h0, const float* __restrict__ hin,
    float* __restrict__ hout,
    const int* __restrict__ flags, void* __restrict__ outp, int write_out)
{
    const int lane = threadIdx.x & 63;
    const int node = blockIdx.x * 4 + (threadIdx.x >> 6);
    if (node >= N_NODES) return;
    int p   = rowptr[node];
    const int end = rowptr[node + 1];
    float acc = 0.0f;
    for (; p + 3 < end; p += 4) {
        int2 e0 = csr[p], e1 = csr[p + 1], e2 = csr[p + 2], e3 = csr[p + 3];
        float v0 = hin[(size_t)e0.x * MY + lane];
        float v1 = hin[(size_t)e1.x * MY + lane];
        float v2 = hin[(size_t)e2.x * MY + lane];
        float v3 = hin[(size_t)e3.x * MY + lane];
        acc += __int_as_float(e0.y) * v0;
        acc += __int_as_float(e1.y) * v1;
        acc += __int_as_float(e2.y) * v2;
        acc += __int_as_float(e3.y) * v3;
    }
    for (; p < end; ++p) {
        int2 e = csr[p];
        acc += __int_as_float(e.y) * hin[(size_t)e.x * MY + lane];
    }
    const size_t o = (size_t)node * MY + lane;
    float dv = dinv[node];
    float r = acc + (1.0f - ALPHA) * dv * dv * hin[o] + ALPHA * h0[o];
    if (write_out) {
        if (flags[0]) ((float*)outp)[o] = r;
        else          ((unsigned short*)outp)[o] = f2us(r);
    } else {
        hout[o] = r;
    }
}

// ---- fallback (atomic push) kernels, used only if ws too small ------------
__global__ __launch_bounds__(256) void self_kernel(
    const float4* __restrict__ h0, const float4* __restrict__ hin,
    const float* __restrict__ dinv, float4* __restrict__ hout)
{
    int idx = blockIdx.x * 256 + threadIdx.x;
    if (idx >= N_NODES * (MY / 4)) return;
    int node = idx / (MY / 4);
    float d = dinv[node];
    float w = (1.0f - ALPHA) * d * d;
    float4 a = h0[idx], b = hin[idx];
    float4 o;
    o.x = ALPHA * a.x + w * b.x;
    o.y = ALPHA * a.y + w * b.y;
    o.z = ALPHA * a.z + w * b.z;
    o.w = ALPHA * a.w + w * b.w;
    hout[idx] = o;
}

__global__ __launch_bounds__(256) void edge_kernel(
    const int* __restrict__ ei, const int* __restrict__ flags,
    const float* __restrict__ dinv,
    const float* __restrict__ hin, float* __restrict__ hout)
{
    int lane = threadIdx.x & 63;
    int e = blockIdx.x * 4 + (threadIdx.x >> 6);
    if (e >= N_EDGES) return;
    int s, d;
    if (flags[1]) { s = ei[2 * e]; d = ei[2 * (N_EDGES + e)]; }
    else          { s = ei[e];     d = ei[N_EDGES + e]; }
    float w = (1.0f - ALPHA) * dinv[s] * dinv[d];
    atomicAdd(&hout[(size_t)d * MY + lane], w * hin[(size_t)s * MY + lane]);
}

__global__ __launch_bounds__(256) void out_kernel(
    const float* __restrict__ h, void* __restrict__ out, const int* __restrict__ flags)
{
    int idx = blockIdx.x * 256 + threadIdx.x;
    if (idx < N_NODES * MY) {
        float v = h[idx];
        if (flags[0]) ((float*)out)[idx] = v;
        else          ((unsigned short*)out)[idx] = f2us(v);
    }
}

// ---------------------------------------------------------------------------
extern "C" void kernel_launch(void* const* d_in, const int* in_sizes, int n_in,
                              void* d_out, int out_size, void* d_ws, size_t ws_size,
                              hipStream_t stream)
{
    const void* x  = d_in[0];
    const void* W1 = d_in[1];
    const void* b1 = d_in[2];
    const void* W2 = d_in[3];
    const void* b2 = d_in[4];
    const int*  ei = (const int*)d_in[5];

    const size_t HN = (size_t)N_NODES * MY;    // 6.4M floats
    // layout: flags(256B) | h0 | hA | hB | dinv | deg | rowptr | fill | csr
    char* base = (char*)d_ws;
    int*   flags  = (int*)base;                     base += 256;
    float* h0     = (float*)base;                   base += HN * 4;
    float* hA     = (float*)base;                   base += HN * 4;
    float* hB     = (float*)base;                   base += HN * 4;
    float* dinv   = (float*)base;                   base += (size_t)N_NODES * 4;
    int*   deg    = (int*)base;                     base += (size_t)N_NODES * 4;
    int*   rowptr = (int*)base;                     base += ((size_t)N_NODES + 4) * 4;
    int*   fill   = (int*)base;                     base += (size_t)N_NODES * 4;
    int2*  csr    = (int2*)base;                    base += (size_t)N_EDGES * 8;
    const size_t need_csr = (size_t)(base - (char*)d_ws);
    const bool use_csr = ws_size >= need_csr;

    detect_kernel<<<1, 256, 0, stream>>>(x, ei, flags);
    zero_deg_kernel<<<(N_NODES + 255) / 256, 256, 0, stream>>>(deg);
    mlp2_kernel<<<256, 256, 0, stream>>>(x, W1, b1, W2, b2, flags, h0);
    deg_kernel<<<(N_EDGES + 255) / 256, 256, 0, stream>>>(ei, flags, deg);
    dinv_kernel<<<(N_NODES + 255) / 256, 256, 0, stream>>>(deg, dinv);

    const float* hin = h0;
    float* hout = hA;
    if (use_csr) {
        scan_kernel<<<1, 256, 0, stream>>>(deg, rowptr, fill);
        fill_kernel<<<(N_EDGES + 255) / 256, 256, 0, stream>>>(
            ei, flags, dinv, rowptr, fill, csr);
        for (int k = 0; k < KITER; ++k) {
            int last = (k == KITER - 1) ? 1 : 0;
            pull_kernel<<<(N_NODES + 3) / 4, 256, 0, stream>>>(
                rowptr, csr, dinv, h0, hin, hout, flags, d_out, last);
            hin = hout;
            hout = (hout == hA) ? hB : hA;
        }
    } else {
        const int n_f4 = N_NODES * (MY / 4);
        for (int k = 0; k < KITER; ++k) {
            self_kernel<<<(n_f4 + 255) / 256, 256, 0, stream>>>(
                (const float4*)h0, (const float4*)hin, dinv, (float4*)hout);
            edge_kernel<<<(N_EDGES + 3) / 4, 256, 0, stream>>>(ei, flags, dinv, hin, hout);
            hin = hout;
            hout = (hout == hA) ? hB : hA;
        }
        out_kernel<<<(N_NODES * MY + 255) / 256, 256, 0, stream>>>(hin, d_out, flags);
    }
}

// Round 5
// 1191.047 us; speedup vs baseline: 3.4346x; 1.1764x over previous
//
#include <hip/hip_runtime.h>
#include <hip/hip_bf16.h>

#define N_NODES 100000
#define N_EDGES 1600000
#define KITER   10
#define ALPHA   0.1f
#define MX      256   // input feature dim
#define MH      64    // hidden dim
#define MY      64    // output feature dim

#define N_SBLK ((N_NODES + 255) / 256)   // 391 scan blocks

typedef __attribute__((ext_vector_type(8))) short bf16x8;   // 8 bf16 = 4 VGPRs
typedef __attribute__((ext_vector_type(4))) float f32x4;

static __device__ __forceinline__ float us2f(unsigned short u) {
    union { unsigned int i; float f; } v; v.i = ((unsigned int)u) << 16; return v.f;
}
static __device__ __forceinline__ unsigned short f2us(float f) {
    union { float f; unsigned int i; } v; v.f = f;
    unsigned int x = v.i;
    unsigned int r = (x + 0x7fffu + ((x >> 16) & 1u)) >> 16;  // RNE
    return (unsigned short)r;
}
static __device__ __forceinline__ float loadf(const void* p, size_t i, int f32) {
    return f32 ? ((const float*)p)[i] : us2f(((const unsigned short*)p)[i]);
}

// ---------------------------------------------------------------------------
// Runtime dtype detection.
// flags[0] = 1 if float inputs are fp32 (else packed bf16)
// flags[1] = 1 if edge_index is int64 (else int32)
// ---------------------------------------------------------------------------
__global__ __launch_bounds__(256) void detect_kernel(
    const void* __restrict__ x, const int* __restrict__ ei, int* __restrict__ flags)
{
    __shared__ int cnt_weird, cnt_nz_odd;
    const int tid = threadIdx.x;
    if (tid == 0) { cnt_weird = 0; cnt_nz_odd = 0; }
    __syncthreads();
    const unsigned short* xu = (const unsigned short*)x;
    int w = 0, nz = 0;
    for (int i = tid; i < 512; i += 256) {
        unsigned e = (xu[2 * i] >> 7) & 0xFFu;     // exponent field if bf16
        if (e != 0u && (e < 105u || e > 141u)) w++;
        if (ei[2 * i + 1] != 0) nz++;              // high word if int64
    }
    atomicAdd(&cnt_weird, w);
    atomicAdd(&cnt_nz_odd, nz);
    __syncthreads();
    if (tid == 0) {
        flags[0] = (cnt_weird > 64) ? 1 : 0;
        flags[1] = (cnt_nz_odd == 0) ? 1 : 0;
    }
}

// ---------------------------------------------------------------------------
// MFMA MLP. Block = 256 threads = 4 waves, 64-node tile, grid-stride.
// ---------------------------------------------------------------------------
#define XS_LD  (MX + 8)   // 264
#define H1_LD  (MH + 8)   // 72
__global__ __launch_bounds__(256) void mlp2_kernel(
    const void* __restrict__ x,
    const void* __restrict__ W1,
    const void* __restrict__ b1,
    const void* __restrict__ W2,
    const void* __restrict__ b2,
    const int* __restrict__ flags,
    float* __restrict__ h0)
{
    __shared__ unsigned short Xs[64][XS_LD];     // 33 KB
    __shared__ unsigned short W1s[MH][XS_LD];    // 33 KB  W1[j][k] row-major
    __shared__ unsigned short H1s[64][H1_LD];    // 9 KB
    __shared__ unsigned short W2s[MY][H1_LD];    // 9 KB   W2[j][k] row-major
    __shared__ float b1s[MH];
    __shared__ float b2s[MY];

    const int f32  = flags[0];
    const int tid  = threadIdx.x;
    const int wave = tid >> 6;
    const int lane = tid & 63;
    const int l16  = lane & 15;
    const int quad = lane >> 4;

    for (int i = tid; i < MH * MX; i += 256) {
        int j = i >> 8, k = i & 255;
        W1s[j][k] = f2us(loadf(W1, i, f32));
    }
    for (int i = tid; i < MY * MH; i += 256) {
        int j = i >> 6, k = i & 63;
        W2s[j][k] = f2us(loadf(W2, i, f32));
    }
    if (tid < MH) b1s[tid] = loadf(b1, tid, f32);
    else if (tid < MH + MY) b2s[tid - MH] = loadf(b2, tid - MH, f32);
    __syncthreads();

    const int n_tiles = (N_NODES + 63) / 64;
    for (int tile = blockIdx.x; tile < n_tiles; tile += gridDim.x) {
        const int base = tile * 64;
        if (f32) {
            for (int i = tid; i < 64 * 64; i += 256) {      // float4 chunks
                int r = i >> 6, c = i & 63;
                int gr = base + r;
                float4 v = make_float4(0.f, 0.f, 0.f, 0.f);
                if (gr < N_NODES)
                    v = ((const float4*)((const float*)x + (size_t)gr * MX))[c];
                ushort4 u;
                u.x = f2us(v.x); u.y = f2us(v.y); u.z = f2us(v.z); u.w = f2us(v.w);
                *(ushort4*)&Xs[r][c * 4] = u;
            }
        } else {
            for (int i = tid; i < 64 * 32; i += 256) {      // 16B chunks
                int r = i >> 5, c = i & 31;
                int gr = base + r;
                uint4 v = make_uint4(0u, 0u, 0u, 0u);
                if (gr < N_NODES)
                    v = ((const uint4*)((const unsigned short*)x + (size_t)gr * MX))[c];
                *(uint4*)&Xs[r][c * 8] = v;
            }
        }
        __syncthreads();

        f32x4 acc[4] = {{0,0,0,0},{0,0,0,0},{0,0,0,0},{0,0,0,0}};
        const int arow = wave * 16 + l16;
        #pragma unroll
        for (int s = 0; s < 8; ++s) {
            const int k0 = s * 32 + quad * 8;
            bf16x8 a = *(const bf16x8*)&Xs[arow][k0];
            #pragma unroll
            for (int cb = 0; cb < 4; ++cb) {
                bf16x8 b = *(const bf16x8*)&W1s[cb * 16 + l16][k0];
                acc[cb] = __builtin_amdgcn_mfma_f32_16x16x32_bf16(a, b, acc[cb], 0, 0, 0);
            }
        }
        #pragma unroll
        for (int cb = 0; cb < 4; ++cb) {
            #pragma unroll
            for (int reg = 0; reg < 4; ++reg) {
                int row = wave * 16 + quad * 4 + reg;
                int col = cb * 16 + l16;
                float v = fmaxf(acc[cb][reg] + b1s[col], 0.0f);
                H1s[row][col] = f2us(v);
            }
        }
        f32x4 acc2[4] = {{0,0,0,0},{0,0,0,0},{0,0,0,0},{0,0,0,0}};
        #pragma unroll
        for (int s = 0; s < 2; ++s) {
            const int k0 = s * 32 + quad * 8;
            bf16x8 a = *(const bf16x8*)&H1s[arow][k0];
            #pragma unroll
            for (int cb = 0; cb < 4; ++cb) {
                bf16x8 b = *(const bf16x8*)&W2s[cb * 16 + l16][k0];
                acc2[cb] = __builtin_amdgcn_mfma_f32_16x16x32_bf16(a, b, acc2[cb], 0, 0, 0);
            }
        }
        #pragma unroll
        for (int cb = 0; cb < 4; ++cb) {
            #pragma unroll
            for (int reg = 0; reg < 4; ++reg) {
                int row = wave * 16 + quad * 4 + reg;
                int col = cb * 16 + l16;
                int gr = base + row;
                if (gr < N_NODES)
                    h0[(size_t)gr * MY + col] = acc2[cb][reg] + b2s[col];
            }
        }
        __syncthreads();
    }
}

// ---------------------------------------------------------------------------
__global__ __launch_bounds__(256) void zero_deg_kernel(int* __restrict__ deg) {
    int i = blockIdx.x * 256 + threadIdx.x;
    if (i < N_NODES) deg[i] = 0;
}

__global__ __launch_bounds__(256) void deg_kernel(
    const int* __restrict__ ei, const int* __restrict__ flags, int* __restrict__ deg)
{
    int e = blockIdx.x * 256 + threadIdx.x;
    if (e < N_EDGES) {
        int d = flags[1] ? ei[2 * (N_EDGES + e)] : ei[N_EDGES + e];
        atomicAdd(&deg[d], 1);
    }
}

__global__ __launch_bounds__(256) void dinv_kernel(
    const int* __restrict__ deg, float* __restrict__ dinv)
{
    int i = blockIdx.x * 256 + threadIdx.x;
    if (i < N_NODES) dinv[i] = rsqrtf((float)(deg[i] + 1)); // +1 self loop
}

// ---- hierarchical exclusive scan: deg -> rowptr ---------------------------
__global__ __launch_bounds__(256) void scan_partial_kernel(
    const int* __restrict__ deg, int* __restrict__ bsum)
{
    __shared__ int red[256];
    const int b = blockIdx.x;
    const int i = b * 256 + threadIdx.x;
    red[threadIdx.x] = (i < N_NODES) ? deg[i] : 0;
    __syncthreads();
    for (int s = 128; s > 0; s >>= 1) {
        if (threadIdx.x < s) red[threadIdx.x] += red[threadIdx.x + s];
        __syncthreads();
    }
    if (threadIdx.x == 0) bsum[b] = red[0];
}

__global__ __launch_bounds__(256) void scan_block_kernel(
    const int* __restrict__ bsum, int* __restrict__ boff)
{
    __shared__ int vals[N_SBLK];
    for (int i = threadIdx.x; i < N_SBLK; i += 256) vals[i] = bsum[i];
    __syncthreads();
    if (threadIdx.x == 0) {
        int run = 0;
        for (int i = 0; i < N_SBLK; ++i) { int v = vals[i]; vals[i] = run; run += v; }
    }
    __syncthreads();
    for (int i = threadIdx.x; i < N_SBLK; i += 256) boff[i] = vals[i];
}

__global__ __launch_bounds__(256) void rowptr_kernel(
    const int* __restrict__ deg, const int* __restrict__ boff,
    int* __restrict__ rowptr, int* __restrict__ fill)
{
    __shared__ int sc[256];
    const int b = blockIdx.x;
    const int i = b * 256 + threadIdx.x;
    const int v = (i < N_NODES) ? deg[i] : 0;
    sc[threadIdx.x] = v;
    __syncthreads();
    #pragma unroll
    for (int s = 1; s < 256; s <<= 1) {       // Hillis-Steele inclusive
        int t = (threadIdx.x >= s) ? sc[threadIdx.x - s] : 0;
        __syncthreads();
        sc[threadIdx.x] += t;
        __syncthreads();
    }
    const int incl = sc[threadIdx.x];
    if (i < N_NODES) { rowptr[i] = boff[b] + incl - v; fill[i] = 0; }
    if (i == N_NODES - 1) rowptr[N_NODES] = boff[b] + incl;
}

// Scatter edges into dst-sorted CSR: csr[pos] = {src, (1-a)*dinv[s]*dinv[d]}
__global__ __launch_bounds__(256) void fill_kernel(
    const int* __restrict__ ei, const int* __restrict__ flags,
    const float* __restrict__ dinv, const int* __restrict__ rowptr,
    int* __restrict__ fill, int2* __restrict__ csr)
{
    int e = blockIdx.x * 256 + threadIdx.x;
    if (e >= N_EDGES) return;
    int s, d;
    if (flags[1]) { s = ei[2 * e]; d = ei[2 * (N_EDGES + e)]; }
    else          { s = ei[e];     d = ei[N_EDGES + e]; }
    float w = (1.0f - ALPHA) * dinv[s] * dinv[d];
    int pos = rowptr[d] + atomicAdd(&fill[d], 1);
    csr[pos] = make_int2(s, __float_as_int(w));
}

// hout[i] = sum_e w_e*hin[src_e] + (1-a)*dinv[i]^2*hin[i] + a*h0[i]
// One wave per node, lane = feature. 4 gathers in flight.
__global__ __launch_bounds__(256) void pull_kernel(
    const int* __restrict__ rowptr, const int2* __restrict__ csr,
    const float* __restrict__ dinv,
    const float* __restrict__ h0, const float* __restrict__ hin,
    float* __restrict__ hout,
    const int* __restrict__ flags, void* __restrict__ outp, int write_out)
{
    const int lane = threadIdx.x & 63;
    const int node = blockIdx.x * 4 + (threadIdx.x >> 6);
    if (node >= N_NODES) return;
    int p   = rowptr[node];
    const int end = rowptr[node + 1];
    float acc = 0.0f;
    for (; p + 3 < end; p += 4) {
        int2 e0 = csr[p], e1 = csr[p + 1], e2 = csr[p + 2], e3 = csr[p + 3];
        float v0 = hin[(size_t)e0.x * MY + lane];
        float v1 = hin[(size_t)e1.x * MY + lane];
        float v2 = hin[(size_t)e2.x * MY + lane];
        float v3 = hin[(size_t)e3.x * MY + lane];
        acc += __int_as_float(e0.y) * v0;
        acc += __int_as_float(e1.y) * v1;
        acc += __int_as_float(e2.y) * v2;
        acc += __int_as_float(e3.y) * v3;
    }
    for (; p < end; ++p) {
        int2 e = csr[p];
        acc += __int_as_float(e.y) * hin[(size_t)e.x * MY + lane];
    }
    const size_t o = (size_t)node * MY + lane;
    float dv = dinv[node];
    float r = acc + (1.0f - ALPHA) * dv * dv * hin[o] + ALPHA * h0[o];
    if (write_out) {
        if (flags[0]) ((float*)outp)[o] = r;
        else          ((unsigned short*)outp)[o] = f2us(r);
    } else {
        hout[o] = r;
    }
}

// ---- fallback (atomic push) kernels, used only if ws too small ------------
__global__ __launch_bounds__(256) void self_kernel(
    const float4* __restrict__ h0, const float4* __restrict__ hin,
    const float* __restrict__ dinv, float4* __restrict__ hout)
{
    int idx = blockIdx.x * 256 + threadIdx.x;
    if (idx >= N_NODES * (MY / 4)) return;
    int node = idx / (MY / 4);
    float d = dinv[node];
    float w = (1.0f - ALPHA) * d * d;
    float4 a = h0[idx], b = hin[idx];
    float4 o;
    o.x = ALPHA * a.x + w * b.x;
    o.y = ALPHA * a.y + w * b.y;
    o.z = ALPHA * a.z + w * b.z;
    o.w = ALPHA * a.w + w * b.w;
    hout[idx] = o;
}

__global__ __launch_bounds__(256) void edge_kernel(
    const int* __restrict__ ei, const int* __restrict__ flags,
    const float* __restrict__ dinv,
    const float* __restrict__ hin, float* __restrict__ hout)
{
    int lane = threadIdx.x & 63;
    int e = blockIdx.x * 4 + (threadIdx.x >> 6);
    if (e >= N_EDGES) return;
    int s, d;
    if (flags[1]) { s = ei[2 * e]; d = ei[2 * (N_EDGES + e)]; }
    else          { s = ei[e];     d = ei[N_EDGES + e]; }
    float w = (1.0f - ALPHA) * dinv[s] * dinv[d];
    atomicAdd(&hout[(size_t)d * MY + lane], w * hin[(size_t)s * MY + lane]);
}

__global__ __launch_bounds__(256) void out_kernel(
    const float* __restrict__ h, void* __restrict__ out, const int* __restrict__ flags)
{
    int idx = blockIdx.x * 256 + threadIdx.x;
    if (idx < N_NODES * MY) {
        float v = h[idx];
        if (flags[0]) ((float*)out)[idx] = v;
        else          ((unsigned short*)out)[idx] = f2us(v);
    }
}

// ---------------------------------------------------------------------------
extern "C" void kernel_launch(void* const* d_in, const int* in_sizes, int n_in,
                              void* d_out, int out_size, void* d_ws, size_t ws_size,
                              hipStream_t stream)
{
    const void* x  = d_in[0];
    const void* W1 = d_in[1];
    const void* b1 = d_in[2];
    const void* W2 = d_in[3];
    const void* b2 = d_in[4];
    const int*  ei = (const int*)d_in[5];

    const size_t HN = (size_t)N_NODES * MY;    // 6.4M floats
    // layout: flags | h0 | hA | hB | dinv | deg | rowptr | fill | bsum | boff | csr
    char* base = (char*)d_ws;
    int*   flags  = (int*)base;                     base += 256;
    float* h0     = (float*)base;                   base += HN * 4;
    float* hA     = (float*)base;                   base += HN * 4;
    float* hB     = (float*)base;                   base += HN * 4;
    float* dinv   = (float*)base;                   base += (size_t)N_NODES * 4;
    int*   deg    = (int*)base;                     base += (size_t)N_NODES * 4;
    int*   rowptr = (int*)base;                     base += ((size_t)N_NODES + 4) * 4;
    int*   fill   = (int*)base;                     base += (size_t)N_NODES * 4;
    int*   bsum   = (int*)base;                     base += ((size_t)N_SBLK + 4) * 4;
    int*   boff   = (int*)base;                     base += ((size_t)N_SBLK + 4) * 4;
    int2*  csr    = (int2*)base;                    base += (size_t)N_EDGES * 8;
    const size_t need_csr = (size_t)(base - (char*)d_ws);
    const bool use_csr = ws_size >= need_csr;

    detect_kernel<<<1, 256, 0, stream>>>(x, ei, flags);
    zero_deg_kernel<<<(N_NODES + 255) / 256, 256, 0, stream>>>(deg);
    mlp2_kernel<<<256, 256, 0, stream>>>(x, W1, b1, W2, b2, flags, h0);
    deg_kernel<<<(N_EDGES + 255) / 256, 256, 0, stream>>>(ei, flags, deg);
    dinv_kernel<<<(N_NODES + 255) / 256, 256, 0, stream>>>(deg, dinv);

    const float* hin = h0;
    float* hout = hA;
    if (use_csr) {
        scan_partial_kernel<<<N_SBLK, 256, 0, stream>>>(deg, bsum);
        scan_block_kernel<<<1, 256, 0, stream>>>(bsum, boff);
        rowptr_kernel<<<N_SBLK, 256, 0, stream>>>(deg, boff, rowptr, fill);
        fill_kernel<<<(N_EDGES + 255) / 256, 256, 0, stream>>>(
            ei, flags, dinv, rowptr, fill, csr);
        for (int k = 0; k < KITER; ++k) {
            int last = (k == KITER - 1) ? 1 : 0;
            pull_kernel<<<(N_NODES + 3) / 4, 256, 0, stream>>>(
                rowptr, csr, dinv, h0, hin, hout, flags, d_out, last);
            hin = hout;
            hout = (hout == hA) ? hB : hA;
        }
    } else {
        const int n_f4 = N_NODES * (MY / 4);
        for (int k = 0; k < KITER; ++k) {
            self_kernel<<<(n_f4 + 255) / 256, 256, 0, stream>>>(
                (const float4*)h0, (const float4*)hin, dinv, (float4*)hout);
            edge_kernel<<<(N_EDGES + 3) / 4, 256, 0, stream>>>(ei, flags, dinv, hin, hout);
            hin = hout;
            hout = (hout == hA) ? hB : hA;
        }
        out_kernel<<<(N_NODES * MY + 255) / 256, 256, 0, stream>>>(hin, d_out, flags);
    }
}

// Round 6
// 1130.910 us; speedup vs baseline: 3.6173x; 1.0532x over previous
//
#include <hip/hip_runtime.h>
#include <hip/hip_bf16.h>
#include <hip/hip_fp16.h>

#define N_NODES 100000
#define N_EDGES 1600000
#define KITER   10
#define ALPHA   0.1f
#define MX      256   // input feature dim
#define MH      64    // hidden dim
#define MY      64    // output feature dim

#define N_SBLK ((N_NODES + 255) / 256)   // 391 scan blocks

typedef __attribute__((ext_vector_type(8))) short bf16x8;   // 8 bf16 = 4 VGPRs
typedef __attribute__((ext_vector_type(4))) float f32x4;

static __device__ __forceinline__ float us2f(unsigned short u) {
    union { unsigned int i; float f; } v; v.i = ((unsigned int)u) << 16; return v.f;
}
static __device__ __forceinline__ unsigned short f2us(float f) {
    union { float f; unsigned int i; } v; v.f = f;
    unsigned int x = v.i;
    unsigned int r = (x + 0x7fffu + ((x >> 16) & 1u)) >> 16;  // RNE
    return (unsigned short)r;
}
static __device__ __forceinline__ float loadf(const void* p, size_t i, int f32) {
    return f32 ? ((const float*)p)[i] : us2f(((const unsigned short*)p)[i]);
}

// ---------------------------------------------------------------------------
// Runtime dtype detection.
// flags[0] = 1 if float inputs are fp32 (else packed bf16)
// flags[1] = 1 if edge_index is int64 (else int32)
// ---------------------------------------------------------------------------
__global__ __launch_bounds__(256) void detect_kernel(
    const void* __restrict__ x, const int* __restrict__ ei, int* __restrict__ flags)
{
    __shared__ int cnt_weird, cnt_nz_odd;
    const int tid = threadIdx.x;
    if (tid == 0) { cnt_weird = 0; cnt_nz_odd = 0; }
    __syncthreads();
    const unsigned short* xu = (const unsigned short*)x;
    int w = 0, nz = 0;
    for (int i = tid; i < 512; i += 256) {
        unsigned e = (xu[2 * i] >> 7) & 0xFFu;     // exponent field if bf16
        if (e != 0u && (e < 105u || e > 141u)) w++;
        if (ei[2 * i + 1] != 0) nz++;              // high word if int64
    }
    atomicAdd(&cnt_weird, w);
    atomicAdd(&cnt_nz_odd, nz);
    __syncthreads();
    if (tid == 0) {
        flags[0] = (cnt_weird > 64) ? 1 : 0;
        flags[1] = (cnt_nz_odd == 0) ? 1 : 0;
    }
}

// ---------------------------------------------------------------------------
// MFMA MLP, LDS-light. One wave per 16 nodes; A-frags straight from global x,
// B-frags straight from global W1/W2 (L1/L2-resident). Only a per-wave 9 KB
// LDS tile for the layer1 C-layout -> layer2 A-layout relayout. No block
// barriers -> occupancy limited by VGPRs, loads pipeline across waves.
// ---------------------------------------------------------------------------
#define H1S_LD 72
__global__ __launch_bounds__(256) void mlp3_kernel(
    const void* __restrict__ x,
    const void* __restrict__ W1,
    const void* __restrict__ b1,
    const void* __restrict__ W2,
    const void* __restrict__ b2,
    const int* __restrict__ flags,
    float* __restrict__ h0,
    __half* __restrict__ h0h)
{
    __shared__ unsigned short Hs[4][16][H1S_LD];   // 9.2 KB, per-wave slices

    const int f32  = flags[0];
    const int tid  = threadIdx.x;
    const int wave = tid >> 6;
    const int lane = tid & 63;
    const int l16  = lane & 15;
    const int quad = lane >> 4;

    const int gw   = blockIdx.x * 4 + wave;        // global wave id
    const int base = gw * 16;
    if (base >= N_NODES) return;
    const int arow = min(base + l16, N_NODES - 1); // clamped load row (row-independent GEMM)

    const unsigned short* xu  = (const unsigned short*)x;
    const float*          xf  = (const float*)x;
    const unsigned short* W1u = (const unsigned short*)W1;
    const float*          W1f = (const float*)W1;
    const unsigned short* W2u = (const unsigned short*)W2;
    const float*          W2f = (const float*)W2;

    // ---- layer 1: C1[16,64] = X[16,256] * W1^T ----
    f32x4 acc[4] = {{0,0,0,0},{0,0,0,0},{0,0,0,0},{0,0,0,0}};
    #pragma unroll
    for (int s = 0; s < 8; ++s) {
        const int k0 = s * 32 + quad * 8;
        bf16x8 a;
        if (f32) {
            const float* p = xf + (size_t)arow * MX + k0;
            float4 u = *(const float4*)p, v = *(const float4*)(p + 4);
            a[0]=(short)f2us(u.x); a[1]=(short)f2us(u.y); a[2]=(short)f2us(u.z); a[3]=(short)f2us(u.w);
            a[4]=(short)f2us(v.x); a[5]=(short)f2us(v.y); a[6]=(short)f2us(v.z); a[7]=(short)f2us(v.w);
        } else {
            a = *(const bf16x8*)(xu + (size_t)arow * MX + k0);
        }
        #pragma unroll
        for (int cb = 0; cb < 4; ++cb) {
            const int brow = cb * 16 + l16;
            bf16x8 b;
            if (f32) {
                const float* p = W1f + (size_t)brow * MX + k0;
                float4 u = *(const float4*)p, v = *(const float4*)(p + 4);
                b[0]=(short)f2us(u.x); b[1]=(short)f2us(u.y); b[2]=(short)f2us(u.z); b[3]=(short)f2us(u.w);
                b[4]=(short)f2us(v.x); b[5]=(short)f2us(v.y); b[6]=(short)f2us(v.z); b[7]=(short)f2us(v.w);
            } else {
                b = *(const bf16x8*)(W1u + (size_t)brow * MX + k0);
            }
            acc[cb] = __builtin_amdgcn_mfma_f32_16x16x32_bf16(a, b, acc[cb], 0, 0, 0);
        }
    }
    // bias + relu -> per-wave LDS tile (C layout -> A layout relayout)
    #pragma unroll
    for (int cb = 0; cb < 4; ++cb) {
        #pragma unroll
        for (int reg = 0; reg < 4; ++reg) {
            const int row = quad * 4 + reg;
            const int col = cb * 16 + l16;
            float v = fmaxf(acc[cb][reg] + loadf(b1, col, f32), 0.0f);
            Hs[wave][row][col] = f2us(v);
        }
    }
    // ---- layer 2: C2[16,64] = relu(C1)[16,64] * W2^T ----
    f32x4 acc2[4] = {{0,0,0,0},{0,0,0,0},{0,0,0,0},{0,0,0,0}};
    #pragma unroll
    for (int s = 0; s < 2; ++s) {
        const int k0 = s * 32 + quad * 8;
        bf16x8 a = *(const bf16x8*)&Hs[wave][l16][k0];
        #pragma unroll
        for (int cb = 0; cb < 4; ++cb) {
            const int brow = cb * 16 + l16;
            bf16x8 b;
            if (f32) {
                const float* p = W2f + (size_t)brow * MH + k0;
                float4 u = *(const float4*)p, v = *(const float4*)(p + 4);
                b[0]=(short)f2us(u.x); b[1]=(short)f2us(u.y); b[2]=(short)f2us(u.z); b[3]=(short)f2us(u.w);
                b[4]=(short)f2us(v.x); b[5]=(short)f2us(v.y); b[6]=(short)f2us(v.z); b[7]=(short)f2us(v.w);
            } else {
                b = *(const bf16x8*)(W2u + (size_t)brow * MH + k0);
            }
            acc2[cb] = __builtin_amdgcn_mfma_f32_16x16x32_bf16(a, b, acc2[cb], 0, 0, 0);
        }
    }
    #pragma unroll
    for (int cb = 0; cb < 4; ++cb) {
        #pragma unroll
        for (int reg = 0; reg < 4; ++reg) {
            const int row = quad * 4 + reg;
            const int col = cb * 16 + l16;
            const int gr  = base + row;
            if (gr < N_NODES) {
                float v = acc2[cb][reg] + loadf(b2, col, f32);
                h0[(size_t)gr * MY + col] = v;
                if (h0h) h0h[(size_t)gr * MY + col] = __float2half(v);
            }
        }
    }
}

// ---------------------------------------------------------------------------
__global__ __launch_bounds__(256) void zero_deg_kernel(int* __restrict__ deg) {
    int i = blockIdx.x * 256 + threadIdx.x;
    if (i < N_NODES) deg[i] = 0;
}

__global__ __launch_bounds__(256) void deg_kernel(
    const int* __restrict__ ei, const int* __restrict__ flags, int* __restrict__ deg)
{
    int e = blockIdx.x * 256 + threadIdx.x;
    if (e < N_EDGES) {
        int d = flags[1] ? ei[2 * (N_EDGES + e)] : ei[N_EDGES + e];
        atomicAdd(&deg[d], 1);
    }
}

__global__ __launch_bounds__(256) void dinv_kernel(
    const int* __restrict__ deg, float* __restrict__ dinv)
{
    int i = blockIdx.x * 256 + threadIdx.x;
    if (i < N_NODES) dinv[i] = rsqrtf((float)(deg[i] + 1)); // +1 self loop
}

// ---- hierarchical exclusive scan: deg -> rowptr ---------------------------
__global__ __launch_bounds__(256) void scan_partial_kernel(
    const int* __restrict__ deg, int* __restrict__ bsum)
{
    __shared__ int red[256];
    const int b = blockIdx.x;
    const int i = b * 256 + threadIdx.x;
    red[threadIdx.x] = (i < N_NODES) ? deg[i] : 0;
    __syncthreads();
    for (int s = 128; s > 0; s >>= 1) {
        if (threadIdx.x < s) red[threadIdx.x] += red[threadIdx.x + s];
        __syncthreads();
    }
    if (threadIdx.x == 0) bsum[b] = red[0];
}

__global__ __launch_bounds__(256) void scan_block_kernel(
    const int* __restrict__ bsum, int* __restrict__ boff)
{
    __shared__ int vals[N_SBLK];
    for (int i = threadIdx.x; i < N_SBLK; i += 256) vals[i] = bsum[i];
    __syncthreads();
    if (threadIdx.x == 0) {
        int run = 0;
        for (int i = 0; i < N_SBLK; ++i) { int v = vals[i]; vals[i] = run; run += v; }
    }
    __syncthreads();
    for (int i = threadIdx.x; i < N_SBLK; i += 256) boff[i] = vals[i];
}

__global__ __launch_bounds__(256) void rowptr_kernel(
    const int* __restrict__ deg, const int* __restrict__ boff,
    int* __restrict__ rowptr, int* __restrict__ fill)
{
    __shared__ int sc[256];
    const int b = blockIdx.x;
    const int i = b * 256 + threadIdx.x;
    const int v = (i < N_NODES) ? deg[i] : 0;
    sc[threadIdx.x] = v;
    __syncthreads();
    #pragma unroll
    for (int s = 1; s < 256; s <<= 1) {       // Hillis-Steele inclusive
        int t = (threadIdx.x >= s) ? sc[threadIdx.x - s] : 0;
        __syncthreads();
        sc[threadIdx.x] += t;
        __syncthreads();
    }
    const int incl = sc[threadIdx.x];
    if (i < N_NODES) { rowptr[i] = boff[b] + incl - v; fill[i] = 0; }
    if (i == N_NODES - 1) rowptr[N_NODES] = boff[b] + incl;
}

// Scatter edges into dst-sorted CSR: csr[pos] = {src, (1-a)*dinv[s]*dinv[d]}
__global__ __launch_bounds__(256) void fill_kernel(
    const int* __restrict__ ei, const int* __restrict__ flags,
    const float* __restrict__ dinv, const int* __restrict__ rowptr,
    int* __restrict__ fill, int2* __restrict__ csr)
{
    int e = blockIdx.x * 256 + threadIdx.x;
    if (e >= N_EDGES) return;
    int s, d;
    if (flags[1]) { s = ei[2 * e]; d = ei[2 * (N_EDGES + e)]; }
    else          { s = ei[e];     d = ei[N_EDGES + e]; }
    float w = (1.0f - ALPHA) * dinv[s] * dinv[d];
    int pos = rowptr[d] + atomicAdd(&fill[d], 1);
    csr[pos] = make_int2(s, __float_as_int(w));
}

// fp16-h pull: hout[i] = sum_e w_e*hin[src_e] + (1-a)*dinv^2*hin[i] + a*h0[i]
// One wave per node, lane = feature (2B gather -> 128B/row).
__global__ __launch_bounds__(256) void pull16_kernel(
    const int* __restrict__ rowptr, const int2* __restrict__ csr,
    const float* __restrict__ dinv,
    const float* __restrict__ h0, const __half* __restrict__ hin,
    __half* __restrict__ hout,
    const int* __restrict__ flags, void* __restrict__ outp, int write_out)
{
    const int lane = threadIdx.x & 63;
    const int node = blockIdx.x * 4 + (threadIdx.x >> 6);
    if (node >= N_NODES) return;
    int p   = rowptr[node];
    const int end = rowptr[node + 1];
    float acc = 0.0f;
    for (; p + 3 < end; p += 4) {
        int2 e0 = csr[p], e1 = csr[p + 1], e2 = csr[p + 2], e3 = csr[p + 3];
        float v0 = __half2float(hin[(size_t)e0.x * MY + lane]);
        float v1 = __half2float(hin[(size_t)e1.x * MY + lane]);
        float v2 = __half2float(hin[(size_t)e2.x * MY + lane]);
        float v3 = __half2float(hin[(size_t)e3.x * MY + lane]);
        acc += __int_as_float(e0.y) * v0;
        acc += __int_as_float(e1.y) * v1;
        acc += __int_as_float(e2.y) * v2;
        acc += __int_as_float(e3.y) * v3;
    }
    for (; p < end; ++p) {
        int2 e = csr[p];
        acc += __int_as_float(e.y) * __half2float(hin[(size_t)e.x * MY + lane]);
    }
    const size_t o = (size_t)node * MY + lane;
    float dv = dinv[node];
    float r = acc + (1.0f - ALPHA) * dv * dv * __half2float(hin[o]) + ALPHA * h0[o];
    if (write_out) {
        if (flags[0]) ((float*)outp)[o] = r;
        else          ((unsigned short*)outp)[o] = f2us(r);
    } else {
        hout[o] = __float2half(r);
    }
}

// fp32-h pull (mid-tier fallback)
__global__ __launch_bounds__(256) void pull_kernel(
    const int* __restrict__ rowptr, const int2* __restrict__ csr,
    const float* __restrict__ dinv,
    const float* __restrict__ h0, const float* __restrict__ hin,
    float* __restrict__ hout,
    const int* __restrict__ flags, void* __restrict__ outp, int write_out)
{
    const int lane = threadIdx.x & 63;
    const int node = blockIdx.x * 4 + (threadIdx.x >> 6);
    if (node >= N_NODES) return;
    int p   = rowptr[node];
    const int end = rowptr[node + 1];
    float acc = 0.0f;
    for (; p + 3 < end; p += 4) {
        int2 e0 = csr[p], e1 = csr[p + 1], e2 = csr[p + 2], e3 = csr[p + 3];
        float v0 = hin[(size_t)e0.x * MY + lane];
        float v1 = hin[(size_t)e1.x * MY + lane];
        float v2 = hin[(size_t)e2.x * MY + lane];
        float v3 = hin[(size_t)e3.x * MY + lane];
        acc += __int_as_float(e0.y) * v0;
        acc += __int_as_float(e1.y) * v1;
        acc += __int_as_float(e2.y) * v2;
        acc += __int_as_float(e3.y) * v3;
    }
    for (; p < end; ++p) {
        int2 e = csr[p];
        acc += __int_as_float(e.y) * hin[(size_t)e.x * MY + lane];
    }
    const size_t o = (size_t)node * MY + lane;
    float dv = dinv[node];
    float r = acc + (1.0f - ALPHA) * dv * dv * hin[o] + ALPHA * h0[o];
    if (write_out) {
        if (flags[0]) ((float*)outp)[o] = r;
        else          ((unsigned short*)outp)[o] = f2us(r);
    } else {
        hout[o] = r;
    }
}

// ---- fallback (atomic push) kernels, used only if ws too small ------------
__global__ __launch_bounds__(256) void self_kernel(
    const float4* __restrict__ h0, const float4* __restrict__ hin,
    const float* __restrict__ dinv, float4* __restrict__ hout)
{
    int idx = blockIdx.x * 256 + threadIdx.x;
    if (idx >= N_NODES * (MY / 4)) return;
    int node = idx / (MY / 4);
    float d = dinv[node];
    float w = (1.0f - ALPHA) * d * d;
    float4 a = h0[idx], b = hin[idx];
    float4 o;
    o.x = ALPHA * a.x + w * b.x;
    o.y = ALPHA * a.y + w * b.y;
    o.z = ALPHA * a.z + w * b.z;
    o.w = ALPHA * a.w + w * b.w;
    hout[idx] = o;
}

__global__ __launch_bounds__(256) void edge_kernel(
    const int* __restrict__ ei, const int* __restrict__ flags,
    const float* __restrict__ dinv,
    const float* __restrict__ hin, float* __restrict__ hout)
{
    int lane = threadIdx.x & 63;
    int e = blockIdx.x * 4 + (threadIdx.x >> 6);
    if (e >= N_EDGES) return;
    int s, d;
    if (flags[1]) { s = ei[2 * e]; d = ei[2 * (N_EDGES + e)]; }
    else          { s = ei[e];     d = ei[N_EDGES + e]; }
    float w = (1.0f - ALPHA) * dinv[s] * dinv[d];
    atomicAdd(&hout[(size_t)d * MY + lane], w * hin[(size_t)s * MY + lane]);
}

__global__ __launch_bounds__(256) void out_kernel(
    const float* __restrict__ h, void* __restrict__ out, const int* __restrict__ flags)
{
    int idx = blockIdx.x * 256 + threadIdx.x;
    if (idx < N_NODES * MY) {
        float v = h[idx];
        if (flags[0]) ((float*)out)[idx] = v;
        else          ((unsigned short*)out)[idx] = f2us(v);
    }
}

// ---------------------------------------------------------------------------
extern "C" void kernel_launch(void* const* d_in, const int* in_sizes, int n_in,
                              void* d_out, int out_size, void* d_ws, size_t ws_size,
                              hipStream_t stream)
{
    const void* x  = d_in[0];
    const void* W1 = d_in[1];
    const void* b1 = d_in[2];
    const void* W2 = d_in[3];
    const void* b2 = d_in[4];
    const int*  ei = (const int*)d_in[5];

    const size_t HN = (size_t)N_NODES * MY;    // 6.4M elements
    // layout: flags | h0 | hA32 | hB32 | dinv | deg | rowptr | fill | bsum | boff
    //         | csr | h0h | hAh | hBh   (fp16 region last, so tiers degrade cleanly)
    char* base = (char*)d_ws;
    int*    flags  = (int*)base;                    base += 256;
    float*  h0     = (float*)base;                  base += HN * 4;
    float*  hA32   = (float*)base;                  base += HN * 4;
    float*  hB32   = (float*)base;                  base += HN * 4;
    float*  dinv   = (float*)base;                  base += (size_t)N_NODES * 4;
    int*    deg    = (int*)base;                    base += (size_t)N_NODES * 4;
    int*    rowptr = (int*)base;                    base += ((size_t)N_NODES + 4) * 4;
    int*    fill   = (int*)base;                    base += (size_t)N_NODES * 4;
    int*    bsum   = (int*)base;                    base += ((size_t)N_SBLK + 4) * 4;
    int*    boff   = (int*)base;                    base += ((size_t)N_SBLK + 4) * 4;
    int2*   csr    = (int2*)base;                   base += (size_t)N_EDGES * 8;
    const size_t need_csr32 = (size_t)(base - (char*)d_ws);
    __half* h0h    = (__half*)base;                 base += HN * 2;
    __half* hAh    = (__half*)base;                 base += HN * 2;
    __half* hBh    = (__half*)base;                 base += HN * 2;
    const size_t need_fp16 = (size_t)(base - (char*)d_ws);
    const int tier = (ws_size >= need_fp16) ? 2 : (ws_size >= need_csr32 ? 1 : 0);

    detect_kernel<<<1, 256, 0, stream>>>(x, ei, flags);
    zero_deg_kernel<<<(N_NODES + 255) / 256, 256, 0, stream>>>(deg);
    mlp3_kernel<<<( (N_NODES + 15)/16 + 3 ) / 4, 256, 0, stream>>>(
        x, W1, b1, W2, b2, flags, h0, tier == 2 ? h0h : (__half*)nullptr);
    deg_kernel<<<(N_EDGES + 255) / 256, 256, 0, stream>>>(ei, flags, deg);
    dinv_kernel<<<(N_NODES + 255) / 256, 256, 0, stream>>>(deg, dinv);

    if (tier >= 1) {
        scan_partial_kernel<<<N_SBLK, 256, 0, stream>>>(deg, bsum);
        scan_block_kernel<<<1, 256, 0, stream>>>(bsum, boff);
        rowptr_kernel<<<N_SBLK, 256, 0, stream>>>(deg, boff, rowptr, fill);
        fill_kernel<<<(N_EDGES + 255) / 256, 256, 0, stream>>>(
            ei, flags, dinv, rowptr, fill, csr);
    }

    if (tier == 2) {
        const __half* hin = h0h;
        __half* hout = hAh;
        for (int k = 0; k < KITER; ++k) {
            int last = (k == KITER - 1) ? 1 : 0;
            pull16_kernel<<<(N_NODES + 3) / 4, 256, 0, stream>>>(
                rowptr, csr, dinv, h0, hin, hout, flags, d_out, last);
            hin = hout;
            hout = (hout == hAh) ? hBh : hAh;
        }
    } else if (tier == 1) {
        const float* hin = h0;
        float* hout = hA32;
        for (int k = 0; k < KITER; ++k) {
            int last = (k == KITER - 1) ? 1 : 0;
            pull_kernel<<<(N_NODES + 3) / 4, 256, 0, stream>>>(
                rowptr, csr, dinv, h0, hin, hout, flags, d_out, last);
            hin = hout;
            hout = (hout == hA32) ? hB32 : hA32;
        }
    } else {
        const float* hin = h0;
        float* hout = hA32;
        const int n_f4 = N_NODES * (MY / 4);
        for (int k = 0; k < KITER; ++k) {
            self_kernel<<<(n_f4 + 255) / 256, 256, 0, stream>>>(
                (const float4*)h0, (const float4*)hin, dinv, (float4*)hout);
            edge_kernel<<<(N_EDGES + 3) / 4, 256, 0, stream>>>(ei, flags, dinv, hin, hout);
            hin = hout;
            hout = (hout == hA32) ? hB32 : hA32;
        }
        out_kernel<<<(N_NODES * MY + 255) / 256, 256, 0, stream>>>(hin, d_out, flags);
    }
}

// Round 7
// 994.610 us; speedup vs baseline: 4.1130x; 1.1370x over previous
//
#include <hip/hip_runtime.h>
#include <hip/hip_bf16.h>
#include <hip/hip_fp16.h>

#define N_NODES 100000
#define N_EDGES 1600000
#define KITER   10
#define ALPHA   0.1f
#define MX      256   // input feature dim
#define MH      64    // hidden dim
#define MY      64    // output feature dim

#define N_SBLK ((N_NODES + 255) / 256)   // 391 scan blocks

typedef __attribute__((ext_vector_type(8))) short bf16x8;   // 8 bf16 = 4 VGPRs
typedef __attribute__((ext_vector_type(4))) float f32x4;

static __device__ __forceinline__ float us2f(unsigned short u) {
    union { unsigned int i; float f; } v; v.i = ((unsigned int)u) << 16; return v.f;
}
static __device__ __forceinline__ unsigned short f2us(float f) {
    union { float f; unsigned int i; } v; v.f = f;
    unsigned int x = v.i;
    unsigned int r = (x + 0x7fffu + ((x >> 16) & 1u)) >> 16;  // RNE
    return (unsigned short)r;
}
static __device__ __forceinline__ float loadf(const void* p, size_t i, int f32) {
    return f32 ? ((const float*)p)[i] : us2f(((const unsigned short*)p)[i]);
}

// ---------------------------------------------------------------------------
// Runtime dtype detection.
// flags[0] = 1 if float inputs are fp32 (else packed bf16)
// flags[1] = 1 if edge_index is int64 (else int32)
// ---------------------------------------------------------------------------
__global__ __launch_bounds__(256) void detect_kernel(
    const void* __restrict__ x, const int* __restrict__ ei, int* __restrict__ flags)
{
    __shared__ int cnt_weird, cnt_nz_odd;
    const int tid = threadIdx.x;
    if (tid == 0) { cnt_weird = 0; cnt_nz_odd = 0; }
    __syncthreads();
    const unsigned short* xu = (const unsigned short*)x;
    int w = 0, nz = 0;
    for (int i = tid; i < 512; i += 256) {
        unsigned e = (xu[2 * i] >> 7) & 0xFFu;     // exponent field if bf16
        if (e != 0u && (e < 105u || e > 141u)) w++;
        if (ei[2 * i + 1] != 0) nz++;              // high word if int64
    }
    atomicAdd(&cnt_weird, w);
    atomicAdd(&cnt_nz_odd, nz);
    __syncthreads();
    if (tid == 0) {
        flags[0] = (cnt_weird > 64) ? 1 : 0;
        flags[1] = (cnt_nz_odd == 0) ? 1 : 0;
    }
}

// ---------------------------------------------------------------------------
// MFMA MLP, LDS-light. One wave per 16 nodes; A-frags straight from global x,
// B-frags from global W1/W2. Per-wave LDS tile for the layer1->layer2
// relayout and for coalesced fp16 output rows. No block barriers.
// ---------------------------------------------------------------------------
#define H1S_LD 72
__global__ __launch_bounds__(256) void mlp3_kernel(
    const void* __restrict__ x,
    const void* __restrict__ W1,
    const void* __restrict__ b1,
    const void* __restrict__ W2,
    const void* __restrict__ b2,
    const int* __restrict__ flags,
    float* __restrict__ h0,          // fp32 out (may be null in fp16 tier)
    __half* __restrict__ h0h)        // fp16 out (may be null)
{
    __shared__ unsigned short Hs[4][16][H1S_LD];   // 9.2 KB, per-wave slices

    const int f32  = flags[0];
    const int tid  = threadIdx.x;
    const int wave = tid >> 6;
    const int lane = tid & 63;
    const int l16  = lane & 15;
    const int quad = lane >> 4;

    const int gw   = blockIdx.x * 4 + wave;        // global wave id
    const int base = gw * 16;
    if (base >= N_NODES) return;
    const int arow = min(base + l16, N_NODES - 1); // clamped load row

    const unsigned short* xu  = (const unsigned short*)x;
    const float*          xf  = (const float*)x;
    const unsigned short* W1u = (const unsigned short*)W1;
    const float*          W1f = (const float*)W1;
    const unsigned short* W2u = (const unsigned short*)W2;
    const float*          W2f = (const float*)W2;

    // ---- layer 1: C1[16,64] = X[16,256] * W1^T ----
    f32x4 acc[4] = {{0,0,0,0},{0,0,0,0},{0,0,0,0},{0,0,0,0}};
    #pragma unroll
    for (int s = 0; s < 8; ++s) {
        const int k0 = s * 32 + quad * 8;
        bf16x8 a;
        if (f32) {
            const float* p = xf + (size_t)arow * MX + k0;
            float4 u = *(const float4*)p, v = *(const float4*)(p + 4);
            a[0]=(short)f2us(u.x); a[1]=(short)f2us(u.y); a[2]=(short)f2us(u.z); a[3]=(short)f2us(u.w);
            a[4]=(short)f2us(v.x); a[5]=(short)f2us(v.y); a[6]=(short)f2us(v.z); a[7]=(short)f2us(v.w);
        } else {
            a = *(const bf16x8*)(xu + (size_t)arow * MX + k0);
        }
        #pragma unroll
        for (int cb = 0; cb < 4; ++cb) {
            const int brow = cb * 16 + l16;
            bf16x8 b;
            if (f32) {
                const float* p = W1f + (size_t)brow * MX + k0;
                float4 u = *(const float4*)p, v = *(const float4*)(p + 4);
                b[0]=(short)f2us(u.x); b[1]=(short)f2us(u.y); b[2]=(short)f2us(u.z); b[3]=(short)f2us(u.w);
                b[4]=(short)f2us(v.x); b[5]=(short)f2us(v.y); b[6]=(short)f2us(v.z); b[7]=(short)f2us(v.w);
            } else {
                b = *(const bf16x8*)(W1u + (size_t)brow * MX + k0);
            }
            acc[cb] = __builtin_amdgcn_mfma_f32_16x16x32_bf16(a, b, acc[cb], 0, 0, 0);
        }
    }
    // bias + relu -> per-wave LDS tile (C layout -> A layout relayout)
    #pragma unroll
    for (int cb = 0; cb < 4; ++cb) {
        #pragma unroll
        for (int reg = 0; reg < 4; ++reg) {
            const int row = quad * 4 + reg;
            const int col = cb * 16 + l16;
            float v = fmaxf(acc[cb][reg] + loadf(b1, col, f32), 0.0f);
            Hs[wave][row][col] = f2us(v);
        }
    }
    // ---- layer 2: C2[16,64] = relu(C1)[16,64] * W2^T ----
    f32x4 acc2[4] = {{0,0,0,0},{0,0,0,0},{0,0,0,0},{0,0,0,0}};
    #pragma unroll
    for (int s = 0; s < 2; ++s) {
        const int k0 = s * 32 + quad * 8;
        bf16x8 a = *(const bf16x8*)&Hs[wave][l16][k0];
        #pragma unroll
        for (int cb = 0; cb < 4; ++cb) {
            const int brow = cb * 16 + l16;
            bf16x8 b;
            if (f32) {
                const float* p = W2f + (size_t)brow * MH + k0;
                float4 u = *(const float4*)p, v = *(const float4*)(p + 4);
                b[0]=(short)f2us(u.x); b[1]=(short)f2us(u.y); b[2]=(short)f2us(u.z); b[3]=(short)f2us(u.w);
                b[4]=(short)f2us(v.x); b[5]=(short)f2us(v.y); b[6]=(short)f2us(v.z); b[7]=(short)f2us(v.w);
            } else {
                b = *(const bf16x8*)(W2u + (size_t)brow * MH + k0);
            }
            acc2[cb] = __builtin_amdgcn_mfma_f32_16x16x32_bf16(a, b, acc2[cb], 0, 0, 0);
        }
    }
    // C2 + b2 back into the (now consumed) per-wave tile as fp16 bits
    #pragma unroll
    for (int cb = 0; cb < 4; ++cb) {
        #pragma unroll
        for (int reg = 0; reg < 4; ++reg) {
            const int row = quad * 4 + reg;
            const int col = cb * 16 + l16;
            float v = acc2[cb][reg] + loadf(b2, col, f32);
            Hs[wave][row][col] = __half_as_ushort(__float2half(v));
        }
    }
    // coalesced output: one 128B fp16 row (or 256B fp32 row) per instruction
    if (h0h) {
        #pragma unroll 4
        for (int r = 0; r < 16; ++r) {
            const int gr = base + r;
            if (gr < N_NODES)
                h0h[(size_t)gr * MY + lane] = __ushort_as_half(Hs[wave][r][lane]);
        }
    }
    if (h0) {
        #pragma unroll 4
        for (int r = 0; r < 16; ++r) {
            const int gr = base + r;
            if (gr < N_NODES)
                h0[(size_t)gr * MY + lane] =
                    __half2float(__ushort_as_half(Hs[wave][r][lane]));
        }
    }
}

// ---------------------------------------------------------------------------
__global__ __launch_bounds__(256) void zero_deg_kernel(int* __restrict__ deg) {
    int i = blockIdx.x * 256 + threadIdx.x;
    if (i < N_NODES) deg[i] = 0;
}

__global__ __launch_bounds__(256) void deg_kernel(
    const int* __restrict__ ei, const int* __restrict__ flags, int* __restrict__ deg)
{
    int e = blockIdx.x * 256 + threadIdx.x;
    if (e < N_EDGES) {
        int d = flags[1] ? ei[2 * (N_EDGES + e)] : ei[N_EDGES + e];
        atomicAdd(&deg[d], 1);
    }
}

__global__ __launch_bounds__(256) void dinv_kernel(
    const int* __restrict__ deg, float* __restrict__ dinv)
{
    int i = blockIdx.x * 256 + threadIdx.x;
    if (i < N_NODES) dinv[i] = rsqrtf((float)(deg[i] + 1)); // +1 self loop
}

// ---- hierarchical exclusive scan: deg -> rowptr ---------------------------
__global__ __launch_bounds__(256) void scan_partial_kernel(
    const int* __restrict__ deg, int* __restrict__ bsum)
{
    __shared__ int red[256];
    const int b = blockIdx.x;
    const int i = b * 256 + threadIdx.x;
    red[threadIdx.x] = (i < N_NODES) ? deg[i] : 0;
    __syncthreads();
    for (int s = 128; s > 0; s >>= 1) {
        if (threadIdx.x < s) red[threadIdx.x] += red[threadIdx.x + s];
        __syncthreads();
    }
    if (threadIdx.x == 0) bsum[b] = red[0];
}

__global__ __launch_bounds__(256) void scan_block_kernel(
    const int* __restrict__ bsum, int* __restrict__ boff)
{
    __shared__ int vals[N_SBLK];
    for (int i = threadIdx.x; i < N_SBLK; i += 256) vals[i] = bsum[i];
    __syncthreads();
    if (threadIdx.x == 0) {
        int run = 0;
        for (int i = 0; i < N_SBLK; ++i) { int v = vals[i]; vals[i] = run; run += v; }
    }
    __syncthreads();
    for (int i = threadIdx.x; i < N_SBLK; i += 256) boff[i] = vals[i];
}

__global__ __launch_bounds__(256) void rowptr_kernel(
    const int* __restrict__ deg, const int* __restrict__ boff,
    int* __restrict__ rowptr, int* __restrict__ fill)
{
    __shared__ int sc[256];
    const int b = blockIdx.x;
    const int i = b * 256 + threadIdx.x;
    const int v = (i < N_NODES) ? deg[i] : 0;
    sc[threadIdx.x] = v;
    __syncthreads();
    #pragma unroll
    for (int s = 1; s < 256; s <<= 1) {       // Hillis-Steele inclusive
        int t = (threadIdx.x >= s) ? sc[threadIdx.x - s] : 0;
        __syncthreads();
        sc[threadIdx.x] += t;
        __syncthreads();
    }
    const int incl = sc[threadIdx.x];
    if (i < N_NODES) { rowptr[i] = boff[b] + incl - v; fill[i] = 0; }
    if (i == N_NODES - 1) rowptr[N_NODES] = boff[b] + incl;
}

// Scatter edges into dst-sorted CSR: csr[pos] = {src, (1-a)*dinv[s]*dinv[d]}
__global__ __launch_bounds__(256) void fill_kernel(
    const int* __restrict__ ei, const int* __restrict__ flags,
    const float* __restrict__ dinv, const int* __restrict__ rowptr,
    int* __restrict__ fill, int2* __restrict__ csr)
{
    int e = blockIdx.x * 256 + threadIdx.x;
    if (e >= N_EDGES) return;
    int s, d;
    if (flags[1]) { s = ei[2 * e]; d = ei[2 * (N_EDGES + e)]; }
    else          { s = ei[e];     d = ei[N_EDGES + e]; }
    float w = (1.0f - ALPHA) * dinv[s] * dinv[d];
    int pos = rowptr[d] + atomicAdd(&fill[d], 1);
    csr[pos] = make_int2(s, __float_as_int(w));
}

// fp16-h pull, 2 edges per wave-instruction:
// lanes 0-31 = edge parity 0, lanes 32-63 = parity 1; lane%32 = feature pair.
// hout[i] = sum_e w_e*hin[src_e] + (1-a)*dinv^2*hin[i] + a*h0h[i]
__global__ __launch_bounds__(256) void pull16v2_kernel(
    const int* __restrict__ rowptr, const int2* __restrict__ csr,
    const float* __restrict__ dinv,
    const __half* __restrict__ h0h, const __half* __restrict__ hin,
    __half* __restrict__ hout,
    const int* __restrict__ flags, void* __restrict__ outp, int write_out)
{
    const int lane    = threadIdx.x & 63;
    const int node    = blockIdx.x * 4 + (threadIdx.x >> 6);
    if (node >= N_NODES) return;
    const int half_id = lane >> 5;        // which edge of the pair
    const int fpair   = lane & 31;        // features 2*fpair, 2*fpair+1

    int p   = rowptr[node];
    const int end = rowptr[node + 1];
    float ax = 0.0f, ay = 0.0f;

    for (; p + 8 <= end; p += 8) {        // 8 edges in flight per wave
        #pragma unroll
        for (int i = 0; i < 4; ++i) {
            int2 e = csr[p + 2 * i + half_id];
            __half2 hv = *((const __half2*)(hin + (size_t)e.x * MY) + fpair);
            float w = __int_as_float(e.y);
            float2 v = __half22float2(hv);
            ax += w * v.x; ay += w * v.y;
        }
    }
    for (; p + 2 <= end; p += 2) {
        int2 e = csr[p + half_id];
        __half2 hv = *((const __half2*)(hin + (size_t)e.x * MY) + fpair);
        float w = __int_as_float(e.y);
        float2 v = __half22float2(hv);
        ax += w * v.x; ay += w * v.y;
    }
    if (p < end && half_id == 0) {        // odd remainder
        int2 e = csr[p];
        __half2 hv = *((const __half2*)(hin + (size_t)e.x * MY) + fpair);
        float w = __int_as_float(e.y);
        float2 v = __half22float2(hv);
        ax += w * v.x; ay += w * v.y;
    }
    ax += __shfl_xor(ax, 32);
    ay += __shfl_xor(ay, 32);

    if (half_id == 0) {
        const size_t o = (size_t)node * MY + fpair * 2;
        const float dv = dinv[node];
        const float ws = (1.0f - ALPHA) * dv * dv;
        float2 hv  = __half22float2(*((const __half2*)(hin + o)));
        float2 h0v = __half22float2(*((const __half2*)(h0h + o)));
        float rx = ax + ws * hv.x + ALPHA * h0v.x;
        float ry = ay + ws * hv.y + ALPHA * h0v.y;
        if (write_out) {
            if (flags[0]) {
                ((float2*)outp)[(size_t)node * 32 + fpair] = make_float2(rx, ry);
            } else {
                ((unsigned int*)outp)[(size_t)node * 32 + fpair] =
                    (unsigned int)f2us(rx) | ((unsigned int)f2us(ry) << 16);
            }
        } else {
            *((__half2*)(hout + o)) = __floats2half2_rn(rx, ry);
        }
    }
}

// fp32-h pull (mid-tier fallback)
__global__ __launch_bounds__(256) void pull_kernel(
    const int* __restrict__ rowptr, const int2* __restrict__ csr,
    const float* __restrict__ dinv,
    const float* __restrict__ h0, const float* __restrict__ hin,
    float* __restrict__ hout,
    const int* __restrict__ flags, void* __restrict__ outp, int write_out)
{
    const int lane = threadIdx.x & 63;
    const int node = blockIdx.x * 4 + (threadIdx.x >> 6);
    if (node >= N_NODES) return;
    int p   = rowptr[node];
    const int end = rowptr[node + 1];
    float acc = 0.0f;
    for (; p + 3 < end; p += 4) {
        int2 e0 = csr[p], e1 = csr[p + 1], e2 = csr[p + 2], e3 = csr[p + 3];
        float v0 = hin[(size_t)e0.x * MY + lane];
        float v1 = hin[(size_t)e1.x * MY + lane];
        float v2 = hin[(size_t)e2.x * MY + lane];
        float v3 = hin[(size_t)e3.x * MY + lane];
        acc += __int_as_float(e0.y) * v0;
        acc += __int_as_float(e1.y) * v1;
        acc += __int_as_float(e2.y) * v2;
        acc += __int_as_float(e3.y) * v3;
    }
    for (; p < end; ++p) {
        int2 e = csr[p];
        acc += __int_as_float(e.y) * hin[(size_t)e.x * MY + lane];
    }
    const size_t o = (size_t)node * MY + lane;
    float dv = dinv[node];
    float r = acc + (1.0f - ALPHA) * dv * dv * hin[o] + ALPHA * h0[o];
    if (write_out) {
        if (flags[0]) ((float*)outp)[o] = r;
        else          ((unsigned short*)outp)[o] = f2us(r);
    } else {
        hout[o] = r;
    }
}

// ---- fallback (atomic push) kernels, used only if ws too small ------------
__global__ __launch_bounds__(256) void self_kernel(
    const float4* __restrict__ h0, const float4* __restrict__ hin,
    const float* __restrict__ dinv, float4* __restrict__ hout)
{
    int idx = blockIdx.x * 256 + threadIdx.x;
    if (idx >= N_NODES * (MY / 4)) return;
    int node = idx / (MY / 4);
    float d = dinv[node];
    float w = (1.0f - ALPHA) * d * d;
    float4 a = h0[idx], b = hin[idx];
    float4 o;
    o.x = ALPHA * a.x + w * b.x;
    o.y = ALPHA * a.y + w * b.y;
    o.z = ALPHA * a.z + w * b.z;
    o.w = ALPHA * a.w + w * b.w;
    hout[idx] = o;
}

__global__ __launch_bounds__(256) void edge_kernel(
    const int* __restrict__ ei, const int* __restrict__ flags,
    const float* __restrict__ dinv,
    const float* __restrict__ hin, float* __restrict__ hout)
{
    int lane = threadIdx.x & 63;
    int e = blockIdx.x * 4 + (threadIdx.x >> 6);
    if (e >= N_EDGES) return;
    int s, d;
    if (flags[1]) { s = ei[2 * e]; d = ei[2 * (N_EDGES + e)]; }
    else          { s = ei[e];     d = ei[N_EDGES + e]; }
    float w = (1.0f - ALPHA) * dinv[s] * dinv[d];
    atomicAdd(&hout[(size_t)d * MY + lane], w * hin[(size_t)s * MY + lane]);
}

__global__ __launch_bounds__(256) void out_kernel(
    const float* __restrict__ h, void* __restrict__ out, const int* __restrict__ flags)
{
    int idx = blockIdx.x * 256 + threadIdx.x;
    if (idx < N_NODES * MY) {
        float v = h[idx];
        if (flags[0]) ((float*)out)[idx] = v;
        else          ((unsigned short*)out)[idx] = f2us(v);
    }
}

// ---------------------------------------------------------------------------
extern "C" void kernel_launch(void* const* d_in, const int* in_sizes, int n_in,
                              void* d_out, int out_size, void* d_ws, size_t ws_size,
                              hipStream_t stream)
{
    const void* x  = d_in[0];
    const void* W1 = d_in[1];
    const void* b1 = d_in[2];
    const void* W2 = d_in[3];
    const void* b2 = d_in[4];
    const int*  ei = (const int*)d_in[5];

    const size_t HN = (size_t)N_NODES * MY;    // 6.4M elements
    char* base = (char*)d_ws;
    int*    flags  = (int*)base;                    base += 256;
    float*  h0     = (float*)base;                  base += HN * 4;
    float*  hA32   = (float*)base;                  base += HN * 4;
    float*  hB32   = (float*)base;                  base += HN * 4;
    float*  dinv   = (float*)base;                  base += (size_t)N_NODES * 4;
    int*    deg    = (int*)base;                    base += (size_t)N_NODES * 4;
    int*    rowptr = (int*)base;                    base += ((size_t)N_NODES + 4) * 4;
    int*    fill   = (int*)base;                    base += (size_t)N_NODES * 4;
    int*    bsum   = (int*)base;                    base += ((size_t)N_SBLK + 4) * 4;
    int*    boff   = (int*)base;                    base += ((size_t)N_SBLK + 4) * 4;
    int2*   csr    = (int2*)base;                   base += (size_t)N_EDGES * 8;
    const size_t need_csr32 = (size_t)(base - (char*)d_ws);
    __half* h0h    = (__half*)base;                 base += HN * 2;
    __half* hAh    = (__half*)base;                 base += HN * 2;
    __half* hBh    = (__half*)base;                 base += HN * 2;
    const size_t need_fp16 = (size_t)(base - (char*)d_ws);
    const int tier = (ws_size >= need_fp16) ? 2 : (ws_size >= need_csr32 ? 1 : 0);

    detect_kernel<<<1, 256, 0, stream>>>(x, ei, flags);
    zero_deg_kernel<<<(N_NODES + 255) / 256, 256, 0, stream>>>(deg);
    mlp3_kernel<<<((N_NODES + 15) / 16 + 3) / 4, 256, 0, stream>>>(
        x, W1, b1, W2, b2, flags,
        tier == 2 ? (float*)nullptr : h0,
        tier == 2 ? h0h : (__half*)nullptr);
    deg_kernel<<<(N_EDGES + 255) / 256, 256, 0, stream>>>(ei, flags, deg);
    dinv_kernel<<<(N_NODES + 255) / 256, 256, 0, stream>>>(deg, dinv);

    if (tier >= 1) {
        scan_partial_kernel<<<N_SBLK, 256, 0, stream>>>(deg, bsum);
        scan_block_kernel<<<1, 256, 0, stream>>>(bsum, boff);
        rowptr_kernel<<<N_SBLK, 256, 0, stream>>>(deg, boff, rowptr, fill);
        fill_kernel<<<(N_EDGES + 255) / 256, 256, 0, stream>>>(
            ei, flags, dinv, rowptr, fill, csr);
    }

    if (tier == 2) {
        const __half* hin = h0h;
        __half* hout = hAh;
        for (int k = 0; k < KITER; ++k) {
            int last = (k == KITER - 1) ? 1 : 0;
            pull16v2_kernel<<<(N_NODES + 3) / 4, 256, 0, stream>>>(
                rowptr, csr, dinv, h0h, hin, hout, flags, d_out, last);
            hin = hout;
            hout = (hout == hAh) ? hBh : hAh;
        }
    } else if (tier == 1) {
        const float* hin = h0;
        float* hout = hA32;
        for (int k = 0; k < KITER; ++k) {
            int last = (k == KITER - 1) ? 1 : 0;
            pull_kernel<<<(N_NODES + 3) / 4, 256, 0, stream>>>(
                rowptr, csr, dinv, h0, hin, hout, flags, d_out, last);
            hin = hout;
            hout = (hout == hA32) ? hB32 : hA32;
        }
    } else {
        const float* hin = h0;
        float* hout = hA32;
        const int n_f4 = N_NODES * (MY / 4);
        for (int k = 0; k < KITER; ++k) {
            self_kernel<<<(n_f4 + 255) / 256, 256, 0, stream>>>(
                (const float4*)h0, (const float4*)hin, dinv, (float4*)hout);
            edge_kernel<<<(N_EDGES + 3) / 4, 256, 0, stream>>>(ei, flags, dinv, hin, hout);
            hin = hout;
            hout = (hout == hA32) ? hB32 : hA32;
        }
        out_kernel<<<(N_NODES * MY + 255) / 256, 256, 0, stream>>>(hin, d_out, flags);
    }
}